// Round 11
// baseline (327.431 us; speedup 1.0000x reference)
//
#include <hip/hip_runtime.h>
#include <hip/hip_bf16.h>
#include <math.h>

typedef __attribute__((ext_vector_type(8))) short short8b;
typedef __attribute__((ext_vector_type(4))) float f32x4;

#define BSZ 32
#define NHW 196
#define M_ROWS 6272
#define MPAD 6400
#define CDIM 512
#define MSZ 16384
#define NCLS 100
#define ALPHA 0.1f
#define RSTR 67   // odd stride: 2-way (free) banks on serial reduce reads

// ---------------- fused: invnorm partials (+counter zero) | bf16 K decomp ----------------
__global__ __launch_bounds__(256) void k_prep(
    const float* __restrict__ q, float* __restrict__ ssq4, int* __restrict__ gcount,
    const float* __restrict__ K, unsigned short* __restrict__ khi)
{
    const int bid = blockIdx.x;
    if (bid < 128) {
        const int b = bid >> 2, cc = bid & 3, n = threadIdx.x;
        if (bid == 0) { gcount[n] = 0; gcount[256 + n] = 0; }
        if (n >= NHW) return;
        const float* base = q + ((size_t)b * CDIM + cc * 128) * NHW + n;
        float ss = 0.f;
#pragma unroll 8
        for (int c = 0; c < 128; ++c) { float v = base[(size_t)c * NHW]; ss = fmaf(v, v, ss); }
        ssq4[(size_t)(b * NHW + n) * 4 + cc] = ss;
    } else {
        const int tid = (bid - 128) * 256 + threadIdx.x;
        const int c4 = tid & 127, key = tid >> 7;
        const int c = c4 << 2;
        const float4 v = *reinterpret_cast<const float4*>(K + (size_t)key * CDIM + c);
        float xs[4] = {v.x, v.y, v.z, v.w};
        unsigned short hs[4];
#pragma unroll
        for (int i = 0; i < 4; ++i) {
            __hip_bfloat16 h = __float2bfloat16(xs[i]);
            hs[i] = *(unsigned short*)&h;
        }
        size_t off = ((size_t)(c >> 5) * MSZ + key) * 32 + (c & 31);
        ushort4 H; H.x = hs[0]; H.y = hs[1]; H.z = hs[2]; H.w = hs[3];
        *reinterpret_cast<ushort4*>(khi + off) = H;
    }
}

// ---------------- normalized Q: bf16 (MFMA layout) + fp32 row-major (repair) ----------------
__global__ __launch_bounds__(256) void k_decomp_q(
    const float* __restrict__ Q, const float* __restrict__ ssq4,
    unsigned short* __restrict__ qhi, float* __restrict__ qn)
{
    __shared__ unsigned short lh[32][65];
    __shared__ float fs[32][65];
    const int t = threadIdx.x;
    const int rb = blockIdx.x % 100, kb = blockIdx.x / 100;
    const int r0 = rb * 64, c0 = kb * 32;
    const int cin = t >> 6, rin = t & 63;
    const int r = r0 + rin;
    float iv = 0.f;
    if (r < M_ROWS) {
        const float4 s4 = *reinterpret_cast<const float4*>(ssq4 + (size_t)r * 4);
        iv = 1.f / fmaxf(sqrtf((s4.x + s4.y) + (s4.z + s4.w)), 1e-12f);
    }
    const int b = r / NHW, n = r - b * NHW;
#pragma unroll
    for (int ci = 0; ci < 8; ++ci) {
        int cl = ci * 4 + cin;
        float x = 0.f;
        if (r < M_ROWS) x = Q[((size_t)(b * CDIM + (c0 + cl))) * NHW + n] * iv;
        __hip_bfloat16 h = __float2bfloat16(x);
        lh[cl][rin] = *(unsigned short*)&h;
        fs[cl][rin] = x;
    }
    __syncthreads();
    const int r2 = t >> 2, seg = t & 3;
    short8b vh;
    float4 f0, f1;
#pragma unroll
    for (int i = 0; i < 8; ++i) vh[i] = (short)lh[seg * 8 + i][r2];
    f0.x = fs[seg * 8 + 0][r2]; f0.y = fs[seg * 8 + 1][r2];
    f0.z = fs[seg * 8 + 2][r2]; f0.w = fs[seg * 8 + 3][r2];
    f1.x = fs[seg * 8 + 4][r2]; f1.y = fs[seg * 8 + 5][r2];
    f1.z = fs[seg * 8 + 6][r2]; f1.w = fs[seg * 8 + 7][r2];
    size_t off = ((size_t)kb * MPAD + r0 + r2) * 32 + seg * 8;
    *(short8b*)(qhi + off) = vh;
    float* qb = qn + (size_t)(r0 + r2) * CDIM + c0 + seg * 8;
    *reinterpret_cast<float4*>(qb) = f0;
    *reinterpret_cast<float4*>(qb + 4) = f1;
}

// ---------------- single-term bf16 MFMA GEMM, 32 KB LDS -> 5 blocks/CU ----------------
__device__ __forceinline__ void gload16(const void* g, void* lds) {
    __builtin_amdgcn_global_load_lds((const __attribute__((address_space(1))) void*)g,
                                     (__attribute__((address_space(3))) void*)lds,
                                     16, 0, 0);
}

__global__ __launch_bounds__(256, 5) void k_mfma(
    const unsigned short* __restrict__ qhi, const unsigned short* __restrict__ khi,
    const int* __restrict__ mvals, const int* __restrict__ tgt,
    float* __restrict__ pmax32, float* __restrict__ ppos, float* __restrict__ pneg)
{
    __shared__ __align__(16) char smem[32768];   // staging; aliased as epilogue scratch
    float* red = (float*)smem;                   // 64-row batches: 64*RSTR*4 = 17.2 KB

    const int tid = threadIdx.x;
    const int w = tid >> 6, l = tid & 63;

    const int xcd = blockIdx.x & 7;
    const int idx = blockIdx.x >> 3;
    const int mt = idx >> 4;
    const int nt = (xcd << 4) | (idx & 15);
    const int r0 = mt * 128, n0 = nt * 128;

    const int srow = l >> 2;
    const int sg8 = (((l & 3) ^ ((l >> 3) & 3)) << 3);
    const int fr = l & 15;
    const int abyte = (fr << 6) + ((((l >> 4) ^ ((l >> 1) & 3))) << 4);

    const int wm = w >> 1, wn = w & 1;
    const int arow0 = wm * 64, bcol0 = wn * 64;

    // mask columns: 4 mvals per thread, registers (no LDS)
    int mvv[4];
#pragma unroll
    for (int n = 0; n < 4; ++n) mvv[n] = mvals[n0 + bcol0 + n * 16 + fr];

    f32x4 acc[4][4];
    const f32x4 zero4 = {0.f, 0.f, 0.f, 0.f};
#pragma unroll
    for (int m = 0; m < 4; ++m)
#pragma unroll
        for (int n = 0; n < 4; ++n) acc[m][n] = zero4;

    for (int ks = 0; ks < 8; ++ks) {
        __syncthreads();
#pragma unroll
        for (int h = 0; h < 2; ++h) {
            const int kb = 2 * ks + h;
            const size_t qb = ((size_t)kb * MPAD + r0) * 32;
            const size_t ko = ((size_t)kb * MSZ + n0) * 32;
#pragma unroll
            for (int j = 0; j < 2; ++j) {
                const int rr = w * 32 + j * 16 + srow;
                const int dst = h * 8192 + w * 2048 + j * 1024;
                gload16(qhi + qb + (size_t)rr * 32 + sg8, smem + dst);
                gload16(khi + ko + (size_t)rr * 32 + sg8, smem + 16384 + dst);
            }
        }
        __syncthreads();
#pragma unroll
        for (int h = 0; h < 2; ++h) {
            const char* bq = smem + h * 8192;
            const char* bk = smem + 16384 + h * 8192;
            short8b bh[4], ah[4];
#pragma unroll
            for (int n = 0; n < 4; ++n)
                bh[n] = *(const short8b*)(bk + ((bcol0 + n * 16) << 6) + abyte);
#pragma unroll
            for (int m = 0; m < 4; ++m)
                ah[m] = *(const short8b*)(bq + ((arow0 + m * 16) << 6) + abyte);
#pragma unroll
            for (int m = 0; m < 4; ++m)
#pragma unroll
                for (int n = 0; n < 4; ++n)
                    acc[m][n] = __builtin_amdgcn_mfma_f32_16x16x32_bf16(ah[m], bh[n], acc[m][n], 0, 0, 0);
        }
    }
    __syncthreads();   // staging reads done; smem reusable as red

    // ---- hoisted correctness masks: a 128-row tile spans <= 2 samples ----
    const int s0 = r0 / NHW;
    int s1 = (r0 + 127) / NHW; if (s1 > 31) s1 = 31;
    const int tg0 = tgt[s0], tg1 = tgt[s1];
    bool c0m[4], c1m[4];
#pragma unroll
    for (int n = 0; n < 4; ++n) {
        c0m[n] = (mvv[n] == tg0);
        c1m[n] = (mvv[n] == tg1);
    }

    // ---- pass 1 (x2 row-batches): masked p/ng -> transpose-reduce ----
#pragma unroll
    for (int b = 0; b < 2; ++b) {
        if (wm == b) {
#pragma unroll
            for (int m = 0; m < 4; ++m) {
#pragma unroll
                for (int rg = 0; rg < 4; ++rg) {
                    const int rloc = arow0 + m * 16 + ((l >> 4) << 2) + rg;
                    const int rglob = r0 + rloc;
                    int samp = rglob / NHW; samp = samp > 31 ? 31 : samp;
                    const bool use0 = (samp == s0);
                    float p = -INFINITY, ng = -INFINITY;
#pragma unroll
                    for (int n = 0; n < 4; ++n) {
                        const float v = acc[m][n][rg];
                        const bool corr = use0 ? c0m[n] : c1m[n];
                        p  = fmaxf(p,  corr ? v : 0.f);   // mask-by-multiply semantics
                        ng = fmaxf(ng, corr ? 0.f : v);
                    }
                    const int rb = rloc & 63;
                    red[rb * RSTR + (wn << 4) + fr] = p;
                    red[rb * RSTR + 34 + (wn << 4) + fr] = ng;
                }
            }
        }
        __syncthreads();
        if (tid < 128) {
            const int row = tid & 63;
            const int base = row * RSTR + ((tid < 64) ? 0 : 34);
            float v = red[base];
#pragma unroll 31
            for (int i = 1; i < 32; ++i) v = fmaxf(v, red[base + i]);
            if (tid < 64) ppos[(size_t)nt * MPAD + r0 + b * 64 + row] = v;
            else          pneg[(size_t)nt * MPAD + r0 + b * 64 + row] = v;
        }
        __syncthreads();
    }

    // ---- pass 2 (x2 row-batches): per-32-key-group maxima -> transpose-reduce ----
#pragma unroll
    for (int b = 0; b < 2; ++b) {
        if (wm == b) {
#pragma unroll
            for (int m = 0; m < 4; ++m) {
#pragma unroll
                for (int rg = 0; rg < 4; ++rg) {
                    const int rloc = arow0 + m * 16 + ((l >> 4) << 2) + rg;
                    const int rb = rloc & 63;
                    const float vh0 = fmaxf(acc[m][0][rg], acc[m][1][rg]);
                    const float vh1 = fmaxf(acc[m][2][rg], acc[m][3][rg]);
                    red[rb * RSTR + (wn << 5) + fr] = vh0;
                    red[rb * RSTR + (wn << 5) + 16 + fr] = vh1;
                }
            }
        }
        __syncthreads();
        {
            const int row = tid >> 2, grp = tid & 3;   // 256 units: 64 rows x 4 grps
            const int base = row * RSTR + (grp << 4);
            float v = red[base];
#pragma unroll 15
            for (int i = 1; i < 16; ++i) v = fmaxf(v, red[base + i]);
            pmax32[(size_t)(r0 + b * 64 + row) * 512 + (nt << 2) + grp] = v;
        }
        __syncthreads();
    }
}

// ---------------- repair pass 1: per-row band scan -> per-group task lists ----------------
// |sim_bf16 - sim_exact| <= 2*2^-9 + eps; candidates in groups with pm >= M - 0.010.
__global__ __launch_bounds__(256) void k_plan(
    const float* __restrict__ pmax32,
    int* __restrict__ gcount, unsigned short* __restrict__ gtasks,
    unsigned long long* __restrict__ packed)
{
    __shared__ float redm[4];
    const int row = blockIdx.x, t = threadIdx.x;
    const float m0 = pmax32[(size_t)row * 512 + t];
    const float m1 = pmax32[(size_t)row * 512 + 256 + t];
    float m = fmaxf(m0, m1);
#pragma unroll
    for (int off = 1; off < 64; off <<= 1) m = fmaxf(m, __shfl_xor(m, off));
    if ((t & 63) == 0) redm[t >> 6] = m;
    __syncthreads();
    const float M = fmaxf(fmaxf(redm[0], redm[1]), fmaxf(redm[2], redm[3]));
    const float thr = M - 0.010f;
    if (t == 0) packed[row] = 0ull;
    if (m0 >= thr) {
        int s = atomicAdd(&gcount[t], 1);
        gtasks[(size_t)t * M_ROWS + s] = (unsigned short)row;
    }
    if (m1 >= thr) {
        int s = atomicAdd(&gcount[256 + t], 1);
        gtasks[(size_t)(256 + t) * M_ROWS + s] = (unsigned short)row;
    }
}

// ---------------- repair pass 2: group-major exact fp32 re-dot ----------------
__device__ __forceinline__ unsigned long long enc_vi(float v, int idx) {
    unsigned u = __float_as_uint(v);
    u = (u & 0x80000000u) ? ~u : (u | 0x80000000u);   // order-preserving
    return ((unsigned long long)u << 32) | (unsigned)(0xFFFFFFFFu - (unsigned)idx);
}

__global__ __launch_bounds__(256, 2) void k_redot(
    const float* __restrict__ qn, const float* __restrict__ mk,
    const int* __restrict__ gcount, const unsigned short* __restrict__ gtasks,
    unsigned long long* __restrict__ packed)
{
    __shared__ float ks[32][516];
    __shared__ float qrow[512];
    __shared__ float part[32][9];
    const int g = blockIdx.x, t = threadIdx.x;
    const int cnt = gcount[g];
    if (cnt == 0) return;
    {
        const float4* src = reinterpret_cast<const float4*>(mk + (size_t)g * 32 * CDIM);
        for (int i = t; i < 4096; i += 256) {
            const int key = i >> 7, pos = i & 127;
            *reinterpret_cast<float4*>(&ks[key][pos << 2]) = src[i];
        }
    }
    const int kj = t & 31, seg = t >> 5;
    for (int i = 0; i < cnt; ++i) {
        const int row = gtasks[(size_t)g * M_ROWS + i];
        *reinterpret_cast<float2*>(&qrow[t * 2]) =
            *reinterpret_cast<const float2*>(qn + (size_t)row * CDIM + t * 2);
        __syncthreads();
        float s = 0.f;
        const float4* kr = reinterpret_cast<const float4*>(&ks[kj][seg * 64]);
        const float4* qr = reinterpret_cast<const float4*>(&qrow[seg * 64]);
#pragma unroll
        for (int u = 0; u < 16; ++u) {
            const float4 a = qr[u], b = kr[u];
            s = fmaf(a.x, b.x, s); s = fmaf(a.y, b.y, s);
            s = fmaf(a.z, b.z, s); s = fmaf(a.w, b.w, s);
        }
        part[kj][seg] = s;
        __syncthreads();
        if (t < 32) {
            float sim = ((part[t][0] + part[t][1]) + (part[t][2] + part[t][3]))
                      + ((part[t][4] + part[t][5]) + (part[t][6] + part[t][7]));
            int ki = g * 32 + t;
#pragma unroll
            for (int off = 1; off < 32; off <<= 1) {
                const float ov = __shfl_xor(sim, off);
                const int   oi = __shfl_xor(ki, off);
                if (ov > sim || (ov == sim && oi < ki)) { sim = ov; ki = oi; }
            }
            if (t == 0)
                atomicMax((unsigned long long*)&packed[row], enc_vi(sim, ki));
        }
        __syncthreads();
    }
}

// ---------------- merge + vote + loss (repaired argmax) ----------------
__global__ __launch_bounds__(256) void k_merge(
    const int* __restrict__ mvals, const int* __restrict__ tgt,
    const unsigned long long* __restrict__ packed,
    const float* __restrict__ ppos, const float* __restrict__ pneg,
    float* __restrict__ out, float* __restrict__ means)
{
    __shared__ int counts[NCLS];
    __shared__ float perloc[256];
    __shared__ int haspos;
    const int b = blockIdx.x, t = threadIdx.x;
    if (t == 0) haspos = 0;
    if (t < NCLS) counts[t] = 0;
    perloc[t] = 0.f;
    __syncthreads();
    const int tg = tgt[b];
    int found = 0;
    for (int i = t; i < MSZ; i += 256) found |= (mvals[i] == tg) ? 1 : 0;
    if (found) atomicOr(&haspos, 1);
    __syncthreads();
    if (t < NHW) {
        const int row = b * NHW + t;
        float p = -INFINITY, ng = -INFINITY;
        for (int c = 0; c < 128; ++c) {      // [chunk][row]: coalesced across t
            p  = fmaxf(p,  ppos[(size_t)c * MPAD + row]);
            ng = fmaxf(ng, pneg[(size_t)c * MPAD + row]);
        }
        const int ri = (int)(0xFFFFFFFFu - (unsigned)(packed[row] & 0xFFFFFFFFull));
        atomicAdd(&counts[mvals[ri]], 1);
        perloc[t] = haspos ? fmaxf(ng - p + ALPHA, 0.f)
                           : fmaxf(ng + ALPHA, 0.f);
    }
    __syncthreads();
    for (int s = 128; s > 0; s >>= 1) {
        if (t < s) perloc[t] += perloc[t + s];
        __syncthreads();
    }
    if (t == 0) {
        int bestc = 0, bestn = counts[0];
        for (int c = 1; c < NCLS; ++c)
            if (counts[c] > bestn) { bestn = counts[c]; bestc = c; }
        out[b] = (float)bestc;
        means[b] = perloc[0] / (float)NHW;
    }
}

__global__ __launch_bounds__(64) void k_final(const float* __restrict__ means,
                                              float* __restrict__ out) {
    if (threadIdx.x == 0) {
        float s = 0.f;
        for (int b = 0; b < BSZ; ++b) s += means[b];
        out[BSZ] = s;
    }
}

// ---------------- fp32 fallback path (round-1 verified) ----------------
#define BM 128
#define BN 128
#define BK 16
#define LDA (BM + 4)
#define LDB (BN + 4)

__global__ __launch_bounds__(256) void k_invnorm(const float* __restrict__ q,
                                                 float* __restrict__ invq) {
    int b = blockIdx.x, n = threadIdx.x;
    if (n >= NHW) return;
    const float* base = q + (size_t)b * CDIM * NHW + n;
    float ss = 0.f;
#pragma unroll 4
    for (int c = 0; c < CDIM; ++c) { float v = base[(size_t)c * NHW]; ss = fmaf(v, v, ss); }
    invq[b * NHW + n] = 1.f / fmaxf(sqrtf(ss), 1e-12f);
}

__global__ __launch_bounds__(256) void k_gemm_reduce(
    const float* __restrict__ Q, const float* __restrict__ Kz,
    const int* __restrict__ mvals, const int* __restrict__ tgt,
    const float* __restrict__ invq,
    float* __restrict__ pmax, int* __restrict__ pidx,
    float* __restrict__ ppos, float* __restrict__ pneg)
{
    __shared__ float As[BK][LDA];
    __shared__ float Bs[BK][LDB];
    __shared__ float run_max[BM];
    __shared__ int   run_idx[BM];
    __shared__ float run_pos[BM];
    __shared__ float run_neg[BM];
    __shared__ int   mv_s[BN];
    __shared__ int   tgt_s[BM];
    __shared__ float inv_s[BM];

    const int t = threadIdx.x;
    const int rt = blockIdx.x % 49;
    const int chunk = blockIdx.x / 49;
    const int r0 = rt * BM;

    if (t < BM) {
        run_max[t] = -INFINITY; run_idx[t] = 0;
        run_pos[t] = -INFINITY; run_neg[t] = -INFINITY;
        int row = r0 + t;
        tgt_s[t] = tgt[row / NHW];
        inv_s[t] = invq[row];
    }
    const int ty = t >> 4, tx = t & 15;
    __syncthreads();

    for (int tile = 0; tile < 8; ++tile) {
        const int key0 = chunk * 1024 + tile * BN;
        if (t < BN) mv_s[t] = mvals[key0 + t];
        float acc[8][8];
#pragma unroll
        for (int i = 0; i < 8; ++i)
#pragma unroll
            for (int j = 0; j < 8; ++j) acc[i][j] = 0.f;

        for (int ks = 0; ks < 32; ++ks) {
            const int c0 = ks * BK;
            __syncthreads();
#pragma unroll
            for (int it = 0; it < 2; ++it) {
                int i = t + it * 256;
                int k = i >> 5;
                int r4 = (i & 31) << 2;
                int row = r0 + r4;
                int b = row / NHW;
                int n = row - b * NHW;
                const float4 v = *reinterpret_cast<const float4*>(
                    Q + ((size_t)(b * CDIM + c0 + k)) * NHW + n);
                float4 w;
                w.x = v.x * inv_s[r4 + 0]; w.y = v.y * inv_s[r4 + 1];
                w.z = v.z * inv_s[r4 + 2]; w.w = v.w * inv_s[r4 + 3];
                *reinterpret_cast<float4*>(&As[k][r4]) = w;
            }
#pragma unroll
            for (int it = 0; it < 2; ++it) {
                int i = t + it * 256;
                int key = i >> 2;
                int cc = (i & 3) << 2;
                const float4 v = *reinterpret_cast<const float4*>(
                    Kz + (size_t)(key0 + key) * CDIM + c0 + cc);
                Bs[cc + 0][key] = v.x; Bs[cc + 1][key] = v.y;
                Bs[cc + 2][key] = v.z; Bs[cc + 3][key] = v.w;
            }
            __syncthreads();
#pragma unroll
            for (int k = 0; k < BK; ++k) {
                float4 a0 = *reinterpret_cast<const float4*>(&As[k][4 * ty]);
                float4 a1 = *reinterpret_cast<const float4*>(&As[k][64 + 4 * ty]);
                float4 b0 = *reinterpret_cast<const float4*>(&Bs[k][4 * tx]);
                float4 b1 = *reinterpret_cast<const float4*>(&Bs[k][64 + 4 * tx]);
                float a[8] = {a0.x, a0.y, a0.z, a0.w, a1.x, a1.y, a1.z, a1.w};
                float bb[8] = {b0.x, b0.y, b0.z, b0.w, b1.x, b1.y, b1.z, b1.w};
#pragma unroll
                for (int i = 0; i < 8; ++i)
#pragma unroll
                    for (int j = 0; j < 8; ++j)
                        acc[i][j] = fmaf(a[i], bb[j], acc[i][j]);
            }
        }
#pragma unroll
        for (int i = 0; i < 8; ++i) {
            int rl = (i < 4) ? (4 * ty + i) : (64 + 4 * ty + i - 4);
            int tgti = tgt_s[rl];
            float vmax = -INFINITY; int vidx = 0;
            float p = -INFINITY, ng = -INFINITY;
#pragma unroll
            for (int j = 0; j < 8; ++j) {
                int cl = (j < 4) ? (4 * tx + j) : (64 + 4 * tx + j - 4);
                float v = acc[i][j];
                int gk = key0 + cl;
                if (v > vmax) { vmax = v; vidx = gk; }
                bool corr = (mv_s[cl] == tgti);
                p  = fmaxf(p,  corr ? v : 0.f);
                ng = fmaxf(ng, corr ? 0.f : v);
            }
#pragma unroll
            for (int off = 1; off < 16; off <<= 1) {
                float om = __shfl_xor(vmax, off, 16);
                int   oi = __shfl_xor(vidx, off, 16);
                float op = __shfl_xor(p,    off, 16);
                float on = __shfl_xor(ng,   off, 16);
                if (om > vmax || (om == vmax && oi < vidx)) { vmax = om; vidx = oi; }
                p = fmaxf(p, op); ng = fmaxf(ng, on);
            }
            if (tx == 0) {
                if (vmax > run_max[rl]) { run_max[rl] = vmax; run_idx[rl] = vidx; }
                run_pos[rl] = fmaxf(run_pos[rl], p);
                run_neg[rl] = fmaxf(run_neg[rl], ng);
            }
        }
        __syncthreads();
    }
    if (t < BM) {
        int row = r0 + t;
        size_t o = (size_t)row * 16 + chunk;
        pmax[o] = run_max[t]; pidx[o] = run_idx[t];
        ppos[o] = run_pos[t]; pneg[o] = run_neg[t];
    }
}

__global__ __launch_bounds__(256) void k_merge_fb(
    const int* __restrict__ mvals, const int* __restrict__ tgt,
    const float* __restrict__ pmax, const int* __restrict__ pidx,
    const float* __restrict__ ppos, const float* __restrict__ pneg,
    float* __restrict__ out, float* __restrict__ means, int nch)
{
    __shared__ int counts[NCLS];
    __shared__ float perloc[256];
    __shared__ int haspos;
    const int b = blockIdx.x, t = threadIdx.x;
    if (t == 0) haspos = 0;
    if (t < NCLS) counts[t] = 0;
    perloc[t] = 0.f;
    __syncthreads();
    const int tg = tgt[b];
    int found = 0;
    for (int i = t; i < MSZ; i += 256) found |= (mvals[i] == tg) ? 1 : 0;
    if (found) atomicOr(&haspos, 1);
    __syncthreads();
    if (t < NHW) {
        int row = b * NHW + t;
        float vmax = -INFINITY; int vidx = 0;
        float p = -INFINITY, ng = -INFINITY;
        for (int c = 0; c < nch; ++c) {
            size_t o = (size_t)row * nch + c;
            float m = pmax[o]; int i_ = pidx[o];
            if (m > vmax || (m == vmax && i_ < vidx)) { vmax = m; vidx = i_; }
            p = fmaxf(p, ppos[o]); ng = fmaxf(ng, pneg[o]);
        }
        atomicAdd(&counts[mvals[vidx]], 1);
        perloc[t] = haspos ? fmaxf(ng - p + ALPHA, 0.f)
                           : fmaxf(ng + ALPHA, 0.f);
    }
    __syncthreads();
    for (int s = 128; s > 0; s >>= 1) {
        if (t < s) perloc[t] += perloc[t + s];
        __syncthreads();
    }
    if (t == 0) {
        int bestc = 0, bestn = counts[0];
        for (int c = 1; c < NCLS; ++c)
            if (counts[c] > bestn) { bestn = counts[c]; bestc = c; }
        out[b] = (float)bestc;
        means[b] = perloc[0] / (float)NHW;
    }
}

extern "C" void kernel_launch(void* const* d_in, const int* in_sizes, int n_in,
                              void* d_out, int out_size, void* d_ws, size_t ws_size,
                              hipStream_t stream) {
    const float* q  = (const float*)d_in[0];
    const int*   tg = (const int*)d_in[1];
    const float* mk = (const float*)d_in[2];
    const int*   mv = (const int*)d_in[3];
    float* out = (float*)d_out;

    unsigned short* khi = (unsigned short*)d_ws;                     // 16.8 MB
    unsigned short* qhi = khi + (size_t)MSZ * CDIM;                  // 6.6 MB
    float* qn     = (float*)(qhi + (size_t)MPAD * CDIM);             // 13.1 MB
    float* ssq4   = qn + (size_t)MPAD * CDIM;                        // 100 KB
    float* pmax32 = ssq4 + (size_t)M_ROWS * 4;                       // 13.1 MB
    float* ppos   = pmax32 + (size_t)MPAD * 512;                     // 3.3 MB
    float* pneg   = ppos + (size_t)MPAD * 128;                       // 3.3 MB
    int*   gcount = (int*)(pneg + (size_t)MPAD * 128);               // 2 KB
    unsigned short* gtasks = (unsigned short*)(gcount + 512);        // 6.4 MB
    unsigned long long* packed = (unsigned long long*)(gtasks + (size_t)512 * M_ROWS); // 50 KB
    float* means  = (float*)(packed + M_ROWS);
    size_t need = (size_t)((char*)(means + BSZ) - (char*)d_ws);

    if (ws_size >= need) {
        k_prep<<<128 + (MSZ * 128) / 256, 256, 0, stream>>>(q, ssq4, gcount, mk, khi);
        k_decomp_q<<<1600, 256, 0, stream>>>(q, ssq4, qhi, qn);
        k_mfma<<<6400, 256, 0, stream>>>(qhi, khi, mv, tg, pmax32, ppos, pneg);
        k_plan<<<M_ROWS, 256, 0, stream>>>(pmax32, gcount, gtasks, packed);
        k_redot<<<512, 256, 0, stream>>>(qn, mk, gcount, gtasks, packed);
        k_merge<<<BSZ, 256, 0, stream>>>(mv, tg, packed, ppos, pneg, out, means);
        k_final<<<1, 64, 0, stream>>>(means, out);
    } else {
        float* invq0  = (float*)d_ws;
        float* pmax0  = invq0 + M_ROWS;
        float* ppos0  = pmax0 + (size_t)M_ROWS * 16;
        float* pneg0  = ppos0 + (size_t)M_ROWS * 16;
        int*   pidx0  = (int*)(pneg0 + (size_t)M_ROWS * 16);
        float* means0 = (float*)(pidx0 + (size_t)M_ROWS * 16);
        k_invnorm<<<BSZ, 256, 0, stream>>>(q, invq0);
        k_gemm_reduce<<<49 * 16, 256, 0, stream>>>(q, mk, mv, tg, invq0,
                                                   pmax0, pidx0, ppos0, pneg0);
        k_merge_fb<<<BSZ, 256, 0, stream>>>(mv, tg, pmax0, pidx0, ppos0, pneg0, out, means0, 16);
        k_final<<<1, 64, 0, stream>>>(means0, out);
    }
}

// Round 12
// 251.408 us; speedup vs baseline: 1.3024x; 1.3024x over previous
//
#include <hip/hip_runtime.h>
#include <hip/hip_bf16.h>
#include <math.h>

typedef __attribute__((ext_vector_type(8))) short short8b;
typedef __attribute__((ext_vector_type(4))) float f32x4;

#define BSZ 32
#define NHW 196
#define M_ROWS 6272
#define MPAD 6400
#define CDIM 512
#define MSZ 16384
#define NCLS 100
#define ALPHA 0.1f
#define RSTR 67   // odd stride: 2-way (free) banks on serial reduce reads

// ---------------- fused: invnorm partials (+counter zero) | bf16 K decomp ----------------
__global__ __launch_bounds__(256) void k_prep(
    const float* __restrict__ q, float* __restrict__ ssq4, int* __restrict__ gcount,
    const float* __restrict__ K, unsigned short* __restrict__ khi)
{
    const int bid = blockIdx.x;
    if (bid < 128) {
        const int b = bid >> 2, cc = bid & 3, n = threadIdx.x;
        if (bid == 0) { gcount[n] = 0; gcount[256 + n] = 0; }
        if (n >= NHW) return;
        const float* base = q + ((size_t)b * CDIM + cc * 128) * NHW + n;
        float ss = 0.f;
#pragma unroll 8
        for (int c = 0; c < 128; ++c) { float v = base[(size_t)c * NHW]; ss = fmaf(v, v, ss); }
        ssq4[(size_t)(b * NHW + n) * 4 + cc] = ss;
    } else {
        const int tid = (bid - 128) * 256 + threadIdx.x;
        const int c4 = tid & 127, key = tid >> 7;
        const int c = c4 << 2;
        const float4 v = *reinterpret_cast<const float4*>(K + (size_t)key * CDIM + c);
        float xs[4] = {v.x, v.y, v.z, v.w};
        unsigned short hs[4];
#pragma unroll
        for (int i = 0; i < 4; ++i) {
            __hip_bfloat16 h = __float2bfloat16(xs[i]);
            hs[i] = *(unsigned short*)&h;
        }
        size_t off = ((size_t)(c >> 5) * MSZ + key) * 32 + (c & 31);
        ushort4 H; H.x = hs[0]; H.y = hs[1]; H.z = hs[2]; H.w = hs[3];
        *reinterpret_cast<ushort4*>(khi + off) = H;
    }
}

// ---------------- normalized Q: bf16 (MFMA layout) + fp32 row-major (repair) ----------------
__global__ __launch_bounds__(256) void k_decomp_q(
    const float* __restrict__ Q, const float* __restrict__ ssq4,
    unsigned short* __restrict__ qhi, float* __restrict__ qn)
{
    __shared__ unsigned short lh[32][65];
    __shared__ float fs[32][65];
    const int t = threadIdx.x;
    const int rb = blockIdx.x % 100, kb = blockIdx.x / 100;
    const int r0 = rb * 64, c0 = kb * 32;
    const int cin = t >> 6, rin = t & 63;
    const int r = r0 + rin;
    float iv = 0.f;
    if (r < M_ROWS) {
        const float4 s4 = *reinterpret_cast<const float4*>(ssq4 + (size_t)r * 4);
        iv = 1.f / fmaxf(sqrtf((s4.x + s4.y) + (s4.z + s4.w)), 1e-12f);
    }
    const int b = r / NHW, n = r - b * NHW;
#pragma unroll
    for (int ci = 0; ci < 8; ++ci) {
        int cl = ci * 4 + cin;
        float x = 0.f;
        if (r < M_ROWS) x = Q[((size_t)(b * CDIM + (c0 + cl))) * NHW + n] * iv;
        __hip_bfloat16 h = __float2bfloat16(x);
        lh[cl][rin] = *(unsigned short*)&h;
        fs[cl][rin] = x;
    }
    __syncthreads();
    const int r2 = t >> 2, seg = t & 3;
    short8b vh;
    float4 f0, f1;
#pragma unroll
    for (int i = 0; i < 8; ++i) vh[i] = (short)lh[seg * 8 + i][r2];
    f0.x = fs[seg * 8 + 0][r2]; f0.y = fs[seg * 8 + 1][r2];
    f0.z = fs[seg * 8 + 2][r2]; f0.w = fs[seg * 8 + 3][r2];
    f1.x = fs[seg * 8 + 4][r2]; f1.y = fs[seg * 8 + 5][r2];
    f1.z = fs[seg * 8 + 6][r2]; f1.w = fs[seg * 8 + 7][r2];
    size_t off = ((size_t)kb * MPAD + r0 + r2) * 32 + seg * 8;
    *(short8b*)(qhi + off) = vh;
    float* qb = qn + (size_t)(r0 + r2) * CDIM + c0 + seg * 8;
    *reinterpret_cast<float4*>(qb) = f0;
    *reinterpret_cast<float4*>(qb + 4) = f1;
}

// ---------------- single-term bf16 MFMA GEMM, 32 KB LDS ----------------
__device__ __forceinline__ void gload16(const void* g, void* lds) {
    __builtin_amdgcn_global_load_lds((const __attribute__((address_space(1))) void*)g,
                                     (__attribute__((address_space(3))) void*)lds,
                                     16, 0, 0);
}

__global__ __launch_bounds__(256, 4) void k_mfma(
    const unsigned short* __restrict__ qhi, const unsigned short* __restrict__ khi,
    const int* __restrict__ mvals, const int* __restrict__ tgt,
    float* __restrict__ pmax32, float* __restrict__ ppos, float* __restrict__ pneg)
{
    __shared__ __align__(16) char smem[32768];   // staging; aliased as epilogue scratch
    float* red = (float*)smem;                   // 64-row batches: 64*RSTR*4 = 17.2 KB

    const int tid = threadIdx.x;
    const int w = tid >> 6, l = tid & 63;

    const int xcd = blockIdx.x & 7;
    const int idx = blockIdx.x >> 3;
    const int mt = idx >> 4;
    const int nt = (xcd << 4) | (idx & 15);
    const int r0 = mt * 128, n0 = nt * 128;

    const int srow = l >> 2;
    const int sg8 = (((l & 3) ^ ((l >> 3) & 3)) << 3);
    const int fr = l & 15;
    const int abyte = (fr << 6) + ((((l >> 4) ^ ((l >> 1) & 3))) << 4);

    const int wm = w >> 1, wn = w & 1;
    const int arow0 = wm * 64, bcol0 = wn * 64;

    // mask columns: 4 mvals per thread, registers (no LDS)
    int mvv[4];
#pragma unroll
    for (int n = 0; n < 4; ++n) mvv[n] = mvals[n0 + bcol0 + n * 16 + fr];

    f32x4 acc[4][4];
    const f32x4 zero4 = {0.f, 0.f, 0.f, 0.f};
#pragma unroll
    for (int m = 0; m < 4; ++m)
#pragma unroll
        for (int n = 0; n < 4; ++n) acc[m][n] = zero4;

    for (int ks = 0; ks < 8; ++ks) {
        __syncthreads();
#pragma unroll
        for (int h = 0; h < 2; ++h) {
            const int kb = 2 * ks + h;
            const size_t qb = ((size_t)kb * MPAD + r0) * 32;
            const size_t ko = ((size_t)kb * MSZ + n0) * 32;
#pragma unroll
            for (int j = 0; j < 2; ++j) {
                const int rr = w * 32 + j * 16 + srow;
                const int dst = h * 8192 + w * 2048 + j * 1024;
                gload16(qhi + qb + (size_t)rr * 32 + sg8, smem + dst);
                gload16(khi + ko + (size_t)rr * 32 + sg8, smem + 16384 + dst);
            }
        }
        __syncthreads();
#pragma unroll
        for (int h = 0; h < 2; ++h) {
            const char* bq = smem + h * 8192;
            const char* bk = smem + 16384 + h * 8192;
            short8b bh[4], ah[4];
#pragma unroll
            for (int n = 0; n < 4; ++n)
                bh[n] = *(const short8b*)(bk + ((bcol0 + n * 16) << 6) + abyte);
#pragma unroll
            for (int m = 0; m < 4; ++m)
                ah[m] = *(const short8b*)(bq + ((arow0 + m * 16) << 6) + abyte);
#pragma unroll
            for (int m = 0; m < 4; ++m)
#pragma unroll
                for (int n = 0; n < 4; ++n)
                    acc[m][n] = __builtin_amdgcn_mfma_f32_16x16x32_bf16(ah[m], bh[n], acc[m][n], 0, 0, 0);
        }
    }
    __syncthreads();   // staging reads done; smem reusable as red

    // ---- hoisted correctness masks: a 128-row tile spans <= 2 samples ----
    const int s0 = r0 / NHW;
    int s1 = (r0 + 127) / NHW; if (s1 > 31) s1 = 31;
    const int tg0 = tgt[s0], tg1 = tgt[s1];
    bool c0m[4], c1m[4];
#pragma unroll
    for (int n = 0; n < 4; ++n) {
        c0m[n] = (mvv[n] == tg0);
        c1m[n] = (mvv[n] == tg1);
    }

    // ---- pass 1 (x2 row-batches): masked p/ng -> transpose-reduce ----
#pragma unroll
    for (int b = 0; b < 2; ++b) {
        if (wm == b) {
#pragma unroll
            for (int m = 0; m < 4; ++m) {
#pragma unroll
                for (int rg = 0; rg < 4; ++rg) {
                    const int rloc = arow0 + m * 16 + ((l >> 4) << 2) + rg;
                    const int rglob = r0 + rloc;
                    int samp = rglob / NHW; samp = samp > 31 ? 31 : samp;
                    const bool use0 = (samp == s0);
                    float p = -INFINITY, ng = -INFINITY;
#pragma unroll
                    for (int n = 0; n < 4; ++n) {
                        const float v = acc[m][n][rg];
                        const bool corr = use0 ? c0m[n] : c1m[n];
                        p  = fmaxf(p,  corr ? v : 0.f);   // mask-by-multiply semantics
                        ng = fmaxf(ng, corr ? 0.f : v);
                    }
                    const int rb = rloc & 63;
                    red[rb * RSTR + (wn << 4) + fr] = p;
                    red[rb * RSTR + 34 + (wn << 4) + fr] = ng;
                }
            }
        }
        __syncthreads();
        if (tid < 128) {
            const int row = tid & 63;
            const int base = row * RSTR + ((tid < 64) ? 0 : 34);
            float v = red[base];
#pragma unroll 31
            for (int i = 1; i < 32; ++i) v = fmaxf(v, red[base + i]);
            if (tid < 64) ppos[(size_t)nt * MPAD + r0 + b * 64 + row] = v;
            else          pneg[(size_t)nt * MPAD + r0 + b * 64 + row] = v;
        }
        __syncthreads();
    }

    // ---- pass 2 (x2 row-batches): per-32-key-group maxima -> transpose-reduce ----
#pragma unroll
    for (int b = 0; b < 2; ++b) {
        if (wm == b) {
#pragma unroll
            for (int m = 0; m < 4; ++m) {
#pragma unroll
                for (int rg = 0; rg < 4; ++rg) {
                    const int rloc = arow0 + m * 16 + ((l >> 4) << 2) + rg;
                    const int rb = rloc & 63;
                    const float vh0 = fmaxf(acc[m][0][rg], acc[m][1][rg]);
                    const float vh1 = fmaxf(acc[m][2][rg], acc[m][3][rg]);
                    red[rb * RSTR + (wn << 5) + fr] = vh0;
                    red[rb * RSTR + (wn << 5) + 16 + fr] = vh1;
                }
            }
        }
        __syncthreads();
        {
            const int row = tid >> 2, grp = tid & 3;   // 256 units: 64 rows x 4 grps
            const int base = row * RSTR + (grp << 4);
            float v = red[base];
#pragma unroll 15
            for (int i = 1; i < 16; ++i) v = fmaxf(v, red[base + i]);
            pmax32[(size_t)(r0 + b * 64 + row) * 512 + (nt << 2) + grp] = v;
        }
        __syncthreads();
    }
}

// ---------------- repair pass 1: per-row band scan -> per-group task lists ----------------
// |sim_bf16 - sim_exact| <= 2*2^-9 + eps; candidates in groups with pm >= M - 0.010.
__global__ __launch_bounds__(256) void k_plan(
    const float* __restrict__ pmax32,
    int* __restrict__ gcount, unsigned short* __restrict__ gtasks,
    unsigned long long* __restrict__ packed)
{
    __shared__ float redm[4];
    const int row = blockIdx.x, t = threadIdx.x;
    const float m0 = pmax32[(size_t)row * 512 + t];
    const float m1 = pmax32[(size_t)row * 512 + 256 + t];
    float m = fmaxf(m0, m1);
#pragma unroll
    for (int off = 1; off < 64; off <<= 1) m = fmaxf(m, __shfl_xor(m, off));
    if ((t & 63) == 0) redm[t >> 6] = m;
    __syncthreads();
    const float M = fmaxf(fmaxf(redm[0], redm[1]), fmaxf(redm[2], redm[3]));
    const float thr = M - 0.010f;
    if (t == 0) packed[row] = 0ull;
    if (m0 >= thr) {
        int s = atomicAdd(&gcount[t], 1);
        gtasks[(size_t)t * M_ROWS + s] = (unsigned short)row;
    }
    if (m1 >= thr) {
        int s = atomicAdd(&gcount[256 + t], 1);
        gtasks[(size_t)(256 + t) * M_ROWS + s] = (unsigned short)row;
    }
}

// ---------------- repair pass 2: group-major exact fp32 re-dot ----------------
__device__ __forceinline__ unsigned long long enc_vi(float v, int idx) {
    unsigned u = __float_as_uint(v);
    u = (u & 0x80000000u) ? ~u : (u | 0x80000000u);   // order-preserving
    return ((unsigned long long)u << 32) | (unsigned)(0xFFFFFFFFu - (unsigned)idx);
}

__global__ __launch_bounds__(256, 2) void k_redot(
    const float* __restrict__ qn, const float* __restrict__ mk,
    const int* __restrict__ gcount, const unsigned short* __restrict__ gtasks,
    unsigned long long* __restrict__ packed)
{
    __shared__ float ks[32][516];
    __shared__ float qrow[512];
    __shared__ float part[32][9];
    const int g = blockIdx.x, t = threadIdx.x;
    const int cnt = gcount[g];
    if (cnt == 0) return;
    {
        const float4* src = reinterpret_cast<const float4*>(mk + (size_t)g * 32 * CDIM);
        for (int i = t; i < 4096; i += 256) {
            const int key = i >> 7, pos = i & 127;
            *reinterpret_cast<float4*>(&ks[key][pos << 2]) = src[i];
        }
    }
    const int kj = t & 31, seg = t >> 5;
    for (int i = 0; i < cnt; ++i) {
        const int row = gtasks[(size_t)g * M_ROWS + i];
        *reinterpret_cast<float2*>(&qrow[t * 2]) =
            *reinterpret_cast<const float2*>(qn + (size_t)row * CDIM + t * 2);
        __syncthreads();
        float s = 0.f;
        const float4* kr = reinterpret_cast<const float4*>(&ks[kj][seg * 64]);
        const float4* qr = reinterpret_cast<const float4*>(&qrow[seg * 64]);
#pragma unroll
        for (int u = 0; u < 16; ++u) {
            const float4 a = qr[u], b = kr[u];
            s = fmaf(a.x, b.x, s); s = fmaf(a.y, b.y, s);
            s = fmaf(a.z, b.z, s); s = fmaf(a.w, b.w, s);
        }
        part[kj][seg] = s;
        __syncthreads();
        if (t < 32) {
            float sim = ((part[t][0] + part[t][1]) + (part[t][2] + part[t][3]))
                      + ((part[t][4] + part[t][5]) + (part[t][6] + part[t][7]));
            int ki = g * 32 + t;
#pragma unroll
            for (int off = 1; off < 32; off <<= 1) {
                const float ov = __shfl_xor(sim, off);
                const int   oi = __shfl_xor(ki, off);
                if (ov > sim || (ov == sim && oi < ki)) { sim = ov; ki = oi; }
            }
            if (t == 0)
                atomicMax((unsigned long long*)&packed[row], enc_vi(sim, ki));
        }
        __syncthreads();
    }
}

// ---------------- merge + vote + loss (repaired argmax) ----------------
__global__ __launch_bounds__(256) void k_merge(
    const int* __restrict__ mvals, const int* __restrict__ tgt,
    const unsigned long long* __restrict__ packed,
    const float* __restrict__ ppos, const float* __restrict__ pneg,
    float* __restrict__ out, float* __restrict__ means)
{
    __shared__ int counts[NCLS];
    __shared__ float perloc[256];
    __shared__ int haspos;
    const int b = blockIdx.x, t = threadIdx.x;
    if (t == 0) haspos = 0;
    if (t < NCLS) counts[t] = 0;
    perloc[t] = 0.f;
    __syncthreads();
    const int tg = tgt[b];
    int found = 0;
    for (int i = t; i < MSZ; i += 256) found |= (mvals[i] == tg) ? 1 : 0;
    if (found) atomicOr(&haspos, 1);
    __syncthreads();
    if (t < NHW) {
        const int row = b * NHW + t;
        float p = -INFINITY, ng = -INFINITY;
        for (int c = 0; c < 128; ++c) {      // [chunk][row]: coalesced across t
            p  = fmaxf(p,  ppos[(size_t)c * MPAD + row]);
            ng = fmaxf(ng, pneg[(size_t)c * MPAD + row]);
        }
        const int ri = (int)(0xFFFFFFFFu - (unsigned)(packed[row] & 0xFFFFFFFFull));
        atomicAdd(&counts[mvals[ri]], 1);
        perloc[t] = haspos ? fmaxf(ng - p + ALPHA, 0.f)
                           : fmaxf(ng + ALPHA, 0.f);
    }
    __syncthreads();
    for (int s = 128; s > 0; s >>= 1) {
        if (t < s) perloc[t] += perloc[t + s];
        __syncthreads();
    }
    if (t == 0) {
        int bestc = 0, bestn = counts[0];
        for (int c = 1; c < NCLS; ++c)
            if (counts[c] > bestn) { bestn = counts[c]; bestc = c; }
        out[b] = (float)bestc;
        means[b] = perloc[0] / (float)NHW;
    }
}

__global__ __launch_bounds__(64) void k_final(const float* __restrict__ means,
                                              float* __restrict__ out) {
    if (threadIdx.x == 0) {
        float s = 0.f;
        for (int b = 0; b < BSZ; ++b) s += means[b];
        out[BSZ] = s;
    }
}

// ---------------- fp32 fallback path (round-1 verified) ----------------
#define BM 128
#define BN 128
#define BK 16
#define LDA (BM + 4)
#define LDB (BN + 4)

__global__ __launch_bounds__(256) void k_invnorm(const float* __restrict__ q,
                                                 float* __restrict__ invq) {
    int b = blockIdx.x, n = threadIdx.x;
    if (n >= NHW) return;
    const float* base = q + (size_t)b * CDIM * NHW + n;
    float ss = 0.f;
#pragma unroll 4
    for (int c = 0; c < CDIM; ++c) { float v = base[(size_t)c * NHW]; ss = fmaf(v, v, ss); }
    invq[b * NHW + n] = 1.f / fmaxf(sqrtf(ss), 1e-12f);
}

__global__ __launch_bounds__(256) void k_gemm_reduce(
    const float* __restrict__ Q, const float* __restrict__ Kz,
    const int* __restrict__ mvals, const int* __restrict__ tgt,
    const float* __restrict__ invq,
    float* __restrict__ pmax, int* __restrict__ pidx,
    float* __restrict__ ppos, float* __restrict__ pneg)
{
    __shared__ float As[BK][LDA];
    __shared__ float Bs[BK][LDB];
    __shared__ float run_max[BM];
    __shared__ int   run_idx[BM];
    __shared__ float run_pos[BM];
    __shared__ float run_neg[BM];
    __shared__ int   mv_s[BN];
    __shared__ int   tgt_s[BM];
    __shared__ float inv_s[BM];

    const int t = threadIdx.x;
    const int rt = blockIdx.x % 49;
    const int chunk = blockIdx.x / 49;
    const int r0 = rt * BM;

    if (t < BM) {
        run_max[t] = -INFINITY; run_idx[t] = 0;
        run_pos[t] = -INFINITY; run_neg[t] = -INFINITY;
        int row = r0 + t;
        tgt_s[t] = tgt[row / NHW];
        inv_s[t] = invq[row];
    }
    const int ty = t >> 4, tx = t & 15;
    __syncthreads();

    for (int tile = 0; tile < 8; ++tile) {
        const int key0 = chunk * 1024 + tile * BN;
        if (t < BN) mv_s[t] = mvals[key0 + t];
        float acc[8][8];
#pragma unroll
        for (int i = 0; i < 8; ++i)
#pragma unroll
            for (int j = 0; j < 8; ++j) acc[i][j] = 0.f;

        for (int ks = 0; ks < 32; ++ks) {
            const int c0 = ks * BK;
            __syncthreads();
#pragma unroll
            for (int it = 0; it < 2; ++it) {
                int i = t + it * 256;
                int k = i >> 5;
                int r4 = (i & 31) << 2;
                int row = r0 + r4;
                int b = row / NHW;
                int n = row - b * NHW;
                const float4 v = *reinterpret_cast<const float4*>(
                    Q + ((size_t)(b * CDIM + c0 + k)) * NHW + n);
                float4 w;
                w.x = v.x * inv_s[r4 + 0]; w.y = v.y * inv_s[r4 + 1];
                w.z = v.z * inv_s[r4 + 2]; w.w = v.w * inv_s[r4 + 3];
                *reinterpret_cast<float4*>(&As[k][r4]) = w;
            }
#pragma unroll
            for (int it = 0; it < 2; ++it) {
                int i = t + it * 256;
                int key = i >> 2;
                int cc = (i & 3) << 2;
                const float4 v = *reinterpret_cast<const float4*>(
                    Kz + (size_t)(key0 + key) * CDIM + c0 + cc);
                Bs[cc + 0][key] = v.x; Bs[cc + 1][key] = v.y;
                Bs[cc + 2][key] = v.z; Bs[cc + 3][key] = v.w;
            }
            __syncthreads();
#pragma unroll
            for (int k = 0; k < BK; ++k) {
                float4 a0 = *reinterpret_cast<const float4*>(&As[k][4 * ty]);
                float4 a1 = *reinterpret_cast<const float4*>(&As[k][64 + 4 * ty]);
                float4 b0 = *reinterpret_cast<const float4*>(&Bs[k][4 * tx]);
                float4 b1 = *reinterpret_cast<const float4*>(&Bs[k][64 + 4 * tx]);
                float a[8] = {a0.x, a0.y, a0.z, a0.w, a1.x, a1.y, a1.z, a1.w};
                float bb[8] = {b0.x, b0.y, b0.z, b0.w, b1.x, b1.y, b1.z, b1.w};
#pragma unroll
                for (int i = 0; i < 8; ++i)
#pragma unroll
                    for (int j = 0; j < 8; ++j)
                        acc[i][j] = fmaf(a[i], bb[j], acc[i][j]);
            }
        }
#pragma unroll
        for (int i = 0; i < 8; ++i) {
            int rl = (i < 4) ? (4 * ty + i) : (64 + 4 * ty + i - 4);
            int tgti = tgt_s[rl];
            float vmax = -INFINITY; int vidx = 0;
            float p = -INFINITY, ng = -INFINITY;
#pragma unroll
            for (int j = 0; j < 8; ++j) {
                int cl = (j < 4) ? (4 * tx + j) : (64 + 4 * tx + j - 4);
                float v = acc[i][j];
                int gk = key0 + cl;
                if (v > vmax) { vmax = v; vidx = gk; }
                bool corr = (mv_s[cl] == tgti);
                p  = fmaxf(p,  corr ? v : 0.f);
                ng = fmaxf(ng, corr ? 0.f : v);
            }
#pragma unroll
            for (int off = 1; off < 16; off <<= 1) {
                float om = __shfl_xor(vmax, off, 16);
                int   oi = __shfl_xor(vidx, off, 16);
                float op = __shfl_xor(p,    off, 16);
                float on = __shfl_xor(ng,   off, 16);
                if (om > vmax || (om == vmax && oi < vidx)) { vmax = om; vidx = oi; }
                p = fmaxf(p, op); ng = fmaxf(ng, on);
            }
            if (tx == 0) {
                if (vmax > run_max[rl]) { run_max[rl] = vmax; run_idx[rl] = vidx; }
                run_pos[rl] = fmaxf(run_pos[rl], p);
                run_neg[rl] = fmaxf(run_neg[rl], ng);
            }
        }
        __syncthreads();
    }
    if (t < BM) {
        int row = r0 + t;
        size_t o = (size_t)row * 16 + chunk;
        pmax[o] = run_max[t]; pidx[o] = run_idx[t];
        ppos[o] = run_pos[t]; pneg[o] = run_neg[t];
    }
}

__global__ __launch_bounds__(256) void k_merge_fb(
    const int* __restrict__ mvals, const int* __restrict__ tgt,
    const float* __restrict__ pmax, const int* __restrict__ pidx,
    const float* __restrict__ ppos, const float* __restrict__ pneg,
    float* __restrict__ out, float* __restrict__ means, int nch)
{
    __shared__ int counts[NCLS];
    __shared__ float perloc[256];
    __shared__ int haspos;
    const int b = blockIdx.x, t = threadIdx.x;
    if (t == 0) haspos = 0;
    if (t < NCLS) counts[t] = 0;
    perloc[t] = 0.f;
    __syncthreads();
    const int tg = tgt[b];
    int found = 0;
    for (int i = t; i < MSZ; i += 256) found |= (mvals[i] == tg) ? 1 : 0;
    if (found) atomicOr(&haspos, 1);
    __syncthreads();
    if (t < NHW) {
        int row = b * NHW + t;
        float vmax = -INFINITY; int vidx = 0;
        float p = -INFINITY, ng = -INFINITY;
        for (int c = 0; c < nch; ++c) {
            size_t o = (size_t)row * nch + c;
            float m = pmax[o]; int i_ = pidx[o];
            if (m > vmax || (m == vmax && i_ < vidx)) { vmax = m; vidx = i_; }
            p = fmaxf(p, ppos[o]); ng = fmaxf(ng, pneg[o]);
        }
        atomicAdd(&counts[mvals[vidx]], 1);
        perloc[t] = haspos ? fmaxf(ng - p + ALPHA, 0.f)
                           : fmaxf(ng + ALPHA, 0.f);
    }
    __syncthreads();
    for (int s = 128; s > 0; s >>= 1) {
        if (t < s) perloc[t] += perloc[t + s];
        __syncthreads();
    }
    if (t == 0) {
        int bestc = 0, bestn = counts[0];
        for (int c = 1; c < NCLS; ++c)
            if (counts[c] > bestn) { bestn = counts[c]; bestc = c; }
        out[b] = (float)bestc;
        means[b] = perloc[0] / (float)NHW;
    }
}

extern "C" void kernel_launch(void* const* d_in, const int* in_sizes, int n_in,
                              void* d_out, int out_size, void* d_ws, size_t ws_size,
                              hipStream_t stream) {
    const float* q  = (const float*)d_in[0];
    const int*   tg = (const int*)d_in[1];
    const float* mk = (const float*)d_in[2];
    const int*   mv = (const int*)d_in[3];
    float* out = (float*)d_out;

    unsigned short* khi = (unsigned short*)d_ws;                     // 16.8 MB
    unsigned short* qhi = khi + (size_t)MSZ * CDIM;                  // 6.6 MB
    float* qn     = (float*)(qhi + (size_t)MPAD * CDIM);             // 13.1 MB
    float* ssq4   = qn + (size_t)MPAD * CDIM;                        // 100 KB
    float* pmax32 = ssq4 + (size_t)M_ROWS * 4;                       // 13.1 MB
    float* ppos   = pmax32 + (size_t)MPAD * 512;                     // 3.3 MB
    float* pneg   = ppos + (size_t)MPAD * 128;                       // 3.3 MB
    int*   gcount = (int*)(pneg + (size_t)MPAD * 128);               // 2 KB
    unsigned short* gtasks = (unsigned short*)(gcount + 512);        // 6.4 MB
    unsigned long long* packed = (unsigned long long*)(gtasks + (size_t)512 * M_ROWS); // 50 KB
    float* means  = (float*)(packed + M_ROWS);
    size_t need = (size_t)((char*)(means + BSZ) - (char*)d_ws);

    if (ws_size >= need) {
        k_prep<<<128 + (MSZ * 128) / 256, 256, 0, stream>>>(q, ssq4, gcount, mk, khi);
        k_decomp_q<<<1600, 256, 0, stream>>>(q, ssq4, qhi, qn);
        k_mfma<<<6400, 256, 0, stream>>>(qhi, khi, mv, tg, pmax32, ppos, pneg);
        k_plan<<<M_ROWS, 256, 0, stream>>>(pmax32, gcount, gtasks, packed);
        k_redot<<<512, 256, 0, stream>>>(qn, mk, gcount, gtasks, packed);
        k_merge<<<BSZ, 256, 0, stream>>>(mv, tg, packed, ppos, pneg, out, means);
        k_final<<<1, 64, 0, stream>>>(means, out);
    } else {
        float* invq0  = (float*)d_ws;
        float* pmax0  = invq0 + M_ROWS;
        float* ppos0  = pmax0 + (size_t)M_ROWS * 16;
        float* pneg0  = ppos0 + (size_t)M_ROWS * 16;
        int*   pidx0  = (int*)(pneg0 + (size_t)M_ROWS * 16);
        float* means0 = (float*)(pidx0 + (size_t)M_ROWS * 16);
        k_invnorm<<<BSZ, 256, 0, stream>>>(q, invq0);
        k_gemm_reduce<<<49 * 16, 256, 0, stream>>>(q, mk, mv, tg, invq0,
                                                   pmax0, pidx0, ppos0, pneg0);
        k_merge_fb<<<BSZ, 256, 0, stream>>>(mv, tg, pmax0, pidx0, ppos0, pneg0, out, means0, 16);
        k_final<<<1, 64, 0, stream>>>(means0, out);
    }
}

// Round 13
// 249.967 us; speedup vs baseline: 1.3099x; 1.0058x over previous
//
#include <hip/hip_runtime.h>
#include <hip/hip_bf16.h>
#include <math.h>

typedef __attribute__((ext_vector_type(8))) short short8b;
typedef __attribute__((ext_vector_type(4))) float f32x4;

#define BSZ 32
#define NHW 196
#define M_ROWS 6272
#define MPAD 6400
#define CDIM 512
#define MSZ 16384
#define NCLS 100
#define ALPHA 0.1f
#define RSTR 67   // odd stride: ~2-way (free) banks on serial reduce reads

// ---------------- fused: invnorm partials (+counter zero) | bf16 K decomp ----------------
__global__ __launch_bounds__(256) void k_prep(
    const float* __restrict__ q, float* __restrict__ ssq4, int* __restrict__ gcount,
    const float* __restrict__ K, unsigned short* __restrict__ khi)
{
    const int bid = blockIdx.x;
    if (bid < 128) {
        const int b = bid >> 2, cc = bid & 3, n = threadIdx.x;
        if (bid == 0) { gcount[n] = 0; gcount[256 + n] = 0; }
        if (n >= NHW) return;
        const float* base = q + ((size_t)b * CDIM + cc * 128) * NHW + n;
        float ss = 0.f;
#pragma unroll 8
        for (int c = 0; c < 128; ++c) { float v = base[(size_t)c * NHW]; ss = fmaf(v, v, ss); }
        ssq4[(size_t)(b * NHW + n) * 4 + cc] = ss;
    } else {
        const int tid = (bid - 128) * 256 + threadIdx.x;
        const int c4 = tid & 127, key = tid >> 7;
        const int c = c4 << 2;
        const float4 v = *reinterpret_cast<const float4*>(K + (size_t)key * CDIM + c);
        float xs[4] = {v.x, v.y, v.z, v.w};
        unsigned short hs[4];
#pragma unroll
        for (int i = 0; i < 4; ++i) {
            __hip_bfloat16 h = __float2bfloat16(xs[i]);
            hs[i] = *(unsigned short*)&h;
        }
        size_t off = ((size_t)(c >> 5) * MSZ + key) * 32 + (c & 31);
        ushort4 H; H.x = hs[0]; H.y = hs[1]; H.z = hs[2]; H.w = hs[3];
        *reinterpret_cast<ushort4*>(khi + off) = H;
    }
}

// ---------------- normalized Q: bf16 (MFMA layout) + fp32 row-major (repair) ----------------
__global__ __launch_bounds__(256) void k_decomp_q(
    const float* __restrict__ Q, const float* __restrict__ ssq4,
    unsigned short* __restrict__ qhi, float* __restrict__ qn)
{
    __shared__ unsigned short lh[32][65];
    __shared__ float fs[32][65];
    const int t = threadIdx.x;
    const int rb = blockIdx.x % 100, kb = blockIdx.x / 100;
    const int r0 = rb * 64, c0 = kb * 32;
    const int cin = t >> 6, rin = t & 63;
    const int r = r0 + rin;
    float iv = 0.f;
    if (r < M_ROWS) {
        const float4 s4 = *reinterpret_cast<const float4*>(ssq4 + (size_t)r * 4);
        iv = 1.f / fmaxf(sqrtf((s4.x + s4.y) + (s4.z + s4.w)), 1e-12f);
    }
    const int b = r / NHW, n = r - b * NHW;
#pragma unroll
    for (int ci = 0; ci < 8; ++ci) {
        int cl = ci * 4 + cin;
        float x = 0.f;
        if (r < M_ROWS) x = Q[((size_t)(b * CDIM + (c0 + cl))) * NHW + n] * iv;
        __hip_bfloat16 h = __float2bfloat16(x);
        lh[cl][rin] = *(unsigned short*)&h;
        fs[cl][rin] = x;
    }
    __syncthreads();
    const int r2 = t >> 2, seg = t & 3;
    short8b vh;
    float4 f0, f1;
#pragma unroll
    for (int i = 0; i < 8; ++i) vh[i] = (short)lh[seg * 8 + i][r2];
    f0.x = fs[seg * 8 + 0][r2]; f0.y = fs[seg * 8 + 1][r2];
    f0.z = fs[seg * 8 + 2][r2]; f0.w = fs[seg * 8 + 3][r2];
    f1.x = fs[seg * 8 + 4][r2]; f1.y = fs[seg * 8 + 5][r2];
    f1.z = fs[seg * 8 + 6][r2]; f1.w = fs[seg * 8 + 7][r2];
    size_t off = ((size_t)kb * MPAD + r0 + r2) * 32 + seg * 8;
    *(short8b*)(qhi + off) = vh;
    float* qb = qn + (size_t)(r0 + r2) * CDIM + c0 + seg * 8;
    *reinterpret_cast<float4*>(qb) = f0;
    *reinterpret_cast<float4*>(qb + 4) = f1;
}

// ---------------- single-term bf16 MFMA GEMM + single-pass transpose epilogue ----------------
__device__ __forceinline__ void gload16(const void* g, void* lds) {
    __builtin_amdgcn_global_load_lds((const __attribute__((address_space(1))) void*)g,
                                     (__attribute__((address_space(3))) void*)lds,
                                     16, 0, 0);
}

__global__ __launch_bounds__(256, 4) void k_mfma(
    const unsigned short* __restrict__ qhi, const unsigned short* __restrict__ khi,
    const int* __restrict__ mvals, const int* __restrict__ tgt,
    float* __restrict__ pmax32, float* __restrict__ ppos, float* __restrict__ pneg)
{
    __shared__ __align__(16) char smem[128 * RSTR * 4];   // 34304 B; staging aliases low 32 KB
    float* red = (float*)smem;

    const int tid = threadIdx.x;
    const int w = tid >> 6, l = tid & 63;

    const int xcd = blockIdx.x & 7;
    const int idx = blockIdx.x >> 3;
    const int mt = idx >> 4;
    const int nt = (xcd << 4) | (idx & 15);
    const int r0 = mt * 128, n0 = nt * 128;

    const int srow = l >> 2;
    const int sg8 = (((l & 3) ^ ((l >> 3) & 3)) << 3);
    const int fr = l & 15;
    const int abyte = (fr << 6) + ((((l >> 4) ^ ((l >> 1) & 3))) << 4);

    const int wm = w >> 1, wn = w & 1;
    const int arow0 = wm * 64, bcol0 = wn * 64;

    // mask columns: 4 mvals per thread, registers (no LDS)
    int mvv[4];
#pragma unroll
    for (int n = 0; n < 4; ++n) mvv[n] = mvals[n0 + bcol0 + n * 16 + fr];

    f32x4 acc[4][4];
    const f32x4 zero4 = {0.f, 0.f, 0.f, 0.f};
#pragma unroll
    for (int m = 0; m < 4; ++m)
#pragma unroll
        for (int n = 0; n < 4; ++n) acc[m][n] = zero4;

    for (int ks = 0; ks < 8; ++ks) {
        __syncthreads();
#pragma unroll
        for (int h = 0; h < 2; ++h) {
            const int kb = 2 * ks + h;
            const size_t qb = ((size_t)kb * MPAD + r0) * 32;
            const size_t ko = ((size_t)kb * MSZ + n0) * 32;
#pragma unroll
            for (int j = 0; j < 2; ++j) {
                const int rr = w * 32 + j * 16 + srow;
                const int dst = h * 8192 + w * 2048 + j * 1024;
                gload16(qhi + qb + (size_t)rr * 32 + sg8, smem + dst);
                gload16(khi + ko + (size_t)rr * 32 + sg8, smem + 16384 + dst);
            }
        }
        __syncthreads();
#pragma unroll
        for (int h = 0; h < 2; ++h) {
            const char* bq = smem + h * 8192;
            const char* bk = smem + 16384 + h * 8192;
            short8b bh[4], ah[4];
#pragma unroll
            for (int n = 0; n < 4; ++n)
                bh[n] = *(const short8b*)(bk + ((bcol0 + n * 16) << 6) + abyte);
#pragma unroll
            for (int m = 0; m < 4; ++m)
                ah[m] = *(const short8b*)(bq + ((arow0 + m * 16) << 6) + abyte);
#pragma unroll
            for (int m = 0; m < 4; ++m)
#pragma unroll
                for (int n = 0; n < 4; ++n)
                    acc[m][n] = __builtin_amdgcn_mfma_f32_16x16x32_bf16(ah[m], bh[n], acc[m][n], 0, 0, 0);
        }
    }
    __syncthreads();   // staging reads done; smem reusable as red

    // ---- hoisted correctness masks: a 128-row tile spans <= 2 samples ----
    const int s0 = r0 / NHW;
    int s1 = (r0 + 127) / NHW; if (s1 > 31) s1 = 31;
    const int tg0 = tgt[s0], tg1 = tgt[s1];
    bool c0m[4], c1m[4];
#pragma unroll
    for (int n = 0; n < 4; ++n) {
        c0m[n] = (mvv[n] == tg0);
        c1m[n] = (mvv[n] == tg1);
    }

    // ---- pass 1: masked p/ng partials -> LDS transpose-reduce (all 128 rows) ----
    // p at [row][wn*16+fr], ng at [row][34+wn*16+fr]
#pragma unroll
    for (int m = 0; m < 4; ++m) {
#pragma unroll
        for (int rg = 0; rg < 4; ++rg) {
            const int rloc = arow0 + m * 16 + ((l >> 4) << 2) + rg;
            const int rglob = r0 + rloc;
            int samp = rglob / NHW; samp = samp > 31 ? 31 : samp;
            const bool use0 = (samp == s0);
            float p = -INFINITY, ng = -INFINITY;
#pragma unroll
            for (int n = 0; n < 4; ++n) {
                const float v = acc[m][n][rg];
                const bool corr = use0 ? c0m[n] : c1m[n];
                p  = fmaxf(p,  corr ? v : 0.f);   // mask-by-multiply semantics
                ng = fmaxf(ng, corr ? 0.f : v);
            }
            red[rloc * RSTR + (wn << 4) + fr] = p;
            red[rloc * RSTR + 34 + (wn << 4) + fr] = ng;
        }
    }
    __syncthreads();
    {
        const int row = tid & 127;
        const int base = row * RSTR + ((tid < 128) ? 0 : 34);
        float v = red[base];
#pragma unroll 31
        for (int i = 1; i < 32; ++i) v = fmaxf(v, red[base + i]);
        if (tid < 128) ppos[(size_t)nt * MPAD + r0 + row] = v;
        else           pneg[(size_t)nt * MPAD + r0 + row] = v;
    }
    __syncthreads();

    // ---- pass 2: per-32-key-group maxima -> LDS transpose-reduce (all 128 rows) ----
#pragma unroll
    for (int m = 0; m < 4; ++m) {
#pragma unroll
        for (int rg = 0; rg < 4; ++rg) {
            const int rloc = arow0 + m * 16 + ((l >> 4) << 2) + rg;
            const float vh0 = fmaxf(acc[m][0][rg], acc[m][1][rg]);
            const float vh1 = fmaxf(acc[m][2][rg], acc[m][3][rg]);
            red[rloc * RSTR + (wn << 5) + fr] = vh0;
            red[rloc * RSTR + (wn << 5) + 16 + fr] = vh1;
        }
    }
    __syncthreads();
#pragma unroll
    for (int uu = 0; uu < 2; ++uu) {
        const int u = tid + uu * 256;        // 512 units: (row, grp)
        const int row = u >> 2, grp = u & 3;
        const int base = row * RSTR + (grp << 4);
        float v = red[base];
#pragma unroll 15
        for (int i = 1; i < 16; ++i) v = fmaxf(v, red[base + i]);
        pmax32[(size_t)(r0 + row) * 512 + (nt << 2) + grp] = v;
    }
}

// ---------------- repair pass 1: per-row band scan -> per-group task lists ----------------
// |sim_bf16 - sim_exact| <= 2*2^-9 + eps; candidates in groups with pm >= M - 0.010.
__global__ __launch_bounds__(256) void k_plan(
    const float* __restrict__ pmax32,
    int* __restrict__ gcount, unsigned short* __restrict__ gtasks,
    unsigned long long* __restrict__ packed)
{
    __shared__ float redm[4];
    const int row = blockIdx.x, t = threadIdx.x;
    const float m0 = pmax32[(size_t)row * 512 + t];
    const float m1 = pmax32[(size_t)row * 512 + 256 + t];
    float m = fmaxf(m0, m1);
#pragma unroll
    for (int off = 1; off < 64; off <<= 1) m = fmaxf(m, __shfl_xor(m, off));
    if ((t & 63) == 0) redm[t >> 6] = m;
    __syncthreads();
    const float M = fmaxf(fmaxf(redm[0], redm[1]), fmaxf(redm[2], redm[3]));
    const float thr = M - 0.010f;
    if (t == 0) packed[row] = 0ull;
    if (m0 >= thr) {
        int s = atomicAdd(&gcount[t], 1);
        gtasks[(size_t)t * M_ROWS + s] = (unsigned short)row;
    }
    if (m1 >= thr) {
        int s = atomicAdd(&gcount[256 + t], 1);
        gtasks[(size_t)(256 + t) * M_ROWS + s] = (unsigned short)row;
    }
}

// ---------------- repair pass 2: group-major exact fp32 re-dot ----------------
__device__ __forceinline__ unsigned long long enc_vi(float v, int idx) {
    unsigned u = __float_as_uint(v);
    u = (u & 0x80000000u) ? ~u : (u | 0x80000000u);   // order-preserving
    return ((unsigned long long)u << 32) | (unsigned)(0xFFFFFFFFu - (unsigned)idx);
}

__global__ __launch_bounds__(256, 2) void k_redot(
    const float* __restrict__ qn, const float* __restrict__ mk,
    const int* __restrict__ gcount, const unsigned short* __restrict__ gtasks,
    unsigned long long* __restrict__ packed)
{
    __shared__ float ks[32][516];
    __shared__ float qrow[512];
    __shared__ float part[32][9];
    const int g = blockIdx.x, t = threadIdx.x;
    const int cnt = gcount[g];
    if (cnt == 0) return;
    {
        const float4* src = reinterpret_cast<const float4*>(mk + (size_t)g * 32 * CDIM);
        for (int i = t; i < 4096; i += 256) {
            const int key = i >> 7, pos = i & 127;
            *reinterpret_cast<float4*>(&ks[key][pos << 2]) = src[i];
        }
    }
    const int kj = t & 31, seg = t >> 5;
    for (int i = 0; i < cnt; ++i) {
        const int row = gtasks[(size_t)g * M_ROWS + i];
        *reinterpret_cast<float2*>(&qrow[t * 2]) =
            *reinterpret_cast<const float2*>(qn + (size_t)row * CDIM + t * 2);
        __syncthreads();
        float s = 0.f;
        const float4* kr = reinterpret_cast<const float4*>(&ks[kj][seg * 64]);
        const float4* qr = reinterpret_cast<const float4*>(&qrow[seg * 64]);
#pragma unroll
        for (int u = 0; u < 16; ++u) {
            const float4 a = qr[u], b = kr[u];
            s = fmaf(a.x, b.x, s); s = fmaf(a.y, b.y, s);
            s = fmaf(a.z, b.z, s); s = fmaf(a.w, b.w, s);
        }
        part[kj][seg] = s;
        __syncthreads();
        if (t < 32) {
            float sim = ((part[t][0] + part[t][1]) + (part[t][2] + part[t][3]))
                      + ((part[t][4] + part[t][5]) + (part[t][6] + part[t][7]));
            int ki = g * 32 + t;
#pragma unroll
            for (int off = 1; off < 32; off <<= 1) {
                const float ov = __shfl_xor(sim, off);
                const int   oi = __shfl_xor(ki, off);
                if (ov > sim || (ov == sim && oi < ki)) { sim = ov; ki = oi; }
            }
            if (t == 0)
                atomicMax((unsigned long long*)&packed[row], enc_vi(sim, ki));
        }
        __syncthreads();
    }
}

// ---------------- merge + vote + loss (repaired argmax) ----------------
__global__ __launch_bounds__(256) void k_merge(
    const int* __restrict__ mvals, const int* __restrict__ tgt,
    const unsigned long long* __restrict__ packed,
    const float* __restrict__ ppos, const float* __restrict__ pneg,
    float* __restrict__ out, float* __restrict__ means)
{
    __shared__ int counts[NCLS];
    __shared__ float perloc[256];
    __shared__ int haspos;
    const int b = blockIdx.x, t = threadIdx.x;
    if (t == 0) haspos = 0;
    if (t < NCLS) counts[t] = 0;
    perloc[t] = 0.f;
    __syncthreads();
    const int tg = tgt[b];
    int found = 0;
    for (int i = t; i < MSZ; i += 256) found |= (mvals[i] == tg) ? 1 : 0;
    if (found) atomicOr(&haspos, 1);
    __syncthreads();
    if (t < NHW) {
        const int row = b * NHW + t;
        float p = -INFINITY, ng = -INFINITY;
        for (int c = 0; c < 128; ++c) {      // [chunk][row]: coalesced across t
            p  = fmaxf(p,  ppos[(size_t)c * MPAD + row]);
            ng = fmaxf(ng, pneg[(size_t)c * MPAD + row]);
        }
        const int ri = (int)(0xFFFFFFFFu - (unsigned)(packed[row] & 0xFFFFFFFFull));
        atomicAdd(&counts[mvals[ri]], 1);
        perloc[t] = haspos ? fmaxf(ng - p + ALPHA, 0.f)
                           : fmaxf(ng + ALPHA, 0.f);
    }
    __syncthreads();
    for (int s = 128; s > 0; s >>= 1) {
        if (t < s) perloc[t] += perloc[t + s];
        __syncthreads();
    }
    if (t == 0) {
        int bestc = 0, bestn = counts[0];
        for (int c = 1; c < NCLS; ++c)
            if (counts[c] > bestn) { bestn = counts[c]; bestc = c; }
        out[b] = (float)bestc;
        means[b] = perloc[0] / (float)NHW;
    }
}

__global__ __launch_bounds__(64) void k_final(const float* __restrict__ means,
                                              float* __restrict__ out) {
    if (threadIdx.x == 0) {
        float s = 0.f;
        for (int b = 0; b < BSZ; ++b) s += means[b];
        out[BSZ] = s;
    }
}

// ---------------- fp32 fallback path (round-1 verified) ----------------
#define BM 128
#define BN 128
#define BK 16
#define LDA (BM + 4)
#define LDB (BN + 4)

__global__ __launch_bounds__(256) void k_invnorm(const float* __restrict__ q,
                                                 float* __restrict__ invq) {
    int b = blockIdx.x, n = threadIdx.x;
    if (n >= NHW) return;
    const float* base = q + (size_t)b * CDIM * NHW + n;
    float ss = 0.f;
#pragma unroll 4
    for (int c = 0; c < CDIM; ++c) { float v = base[(size_t)c * NHW]; ss = fmaf(v, v, ss); }
    invq[b * NHW + n] = 1.f / fmaxf(sqrtf(ss), 1e-12f);
}

__global__ __launch_bounds__(256) void k_gemm_reduce(
    const float* __restrict__ Q, const float* __restrict__ Kz,
    const int* __restrict__ mvals, const int* __restrict__ tgt,
    const float* __restrict__ invq,
    float* __restrict__ pmax, int* __restrict__ pidx,
    float* __restrict__ ppos, float* __restrict__ pneg)
{
    __shared__ float As[BK][LDA];
    __shared__ float Bs[BK][LDB];
    __shared__ float run_max[BM];
    __shared__ int   run_idx[BM];
    __shared__ float run_pos[BM];
    __shared__ float run_neg[BM];
    __shared__ int   mv_s[BN];
    __shared__ int   tgt_s[BM];
    __shared__ float inv_s[BM];

    const int t = threadIdx.x;
    const int rt = blockIdx.x % 49;
    const int chunk = blockIdx.x / 49;
    const int r0 = rt * BM;

    if (t < BM) {
        run_max[t] = -INFINITY; run_idx[t] = 0;
        run_pos[t] = -INFINITY; run_neg[t] = -INFINITY;
        int row = r0 + t;
        tgt_s[t] = tgt[row / NHW];
        inv_s[t] = invq[row];
    }
    const int ty = t >> 4, tx = t & 15;
    __syncthreads();

    for (int tile = 0; tile < 8; ++tile) {
        const int key0 = chunk * 1024 + tile * BN;
        if (t < BN) mv_s[t] = mvals[key0 + t];
        float acc[8][8];
#pragma unroll
        for (int i = 0; i < 8; ++i)
#pragma unroll
            for (int j = 0; j < 8; ++j) acc[i][j] = 0.f;

        for (int ks = 0; ks < 32; ++ks) {
            const int c0 = ks * BK;
            __syncthreads();
#pragma unroll
            for (int it = 0; it < 2; ++it) {
                int i = t + it * 256;
                int k = i >> 5;
                int r4 = (i & 31) << 2;
                int row = r0 + r4;
                int b = row / NHW;
                int n = row - b * NHW;
                const float4 v = *reinterpret_cast<const float4*>(
                    Q + ((size_t)(b * CDIM + c0 + k)) * NHW + n);
                float4 w;
                w.x = v.x * inv_s[r4 + 0]; w.y = v.y * inv_s[r4 + 1];
                w.z = v.z * inv_s[r4 + 2]; w.w = v.w * inv_s[r4 + 3];
                *reinterpret_cast<float4*>(&As[k][r4]) = w;
            }
#pragma unroll
            for (int it = 0; it < 2; ++it) {
                int i = t + it * 256;
                int key = i >> 2;
                int cc = (i & 3) << 2;
                const float4 v = *reinterpret_cast<const float4*>(
                    Kz + (size_t)(key0 + key) * CDIM + c0 + cc);
                Bs[cc + 0][key] = v.x; Bs[cc + 1][key] = v.y;
                Bs[cc + 2][key] = v.z; Bs[cc + 3][key] = v.w;
            }
            __syncthreads();
#pragma unroll
            for (int k = 0; k < BK; ++k) {
                float4 a0 = *reinterpret_cast<const float4*>(&As[k][4 * ty]);
                float4 a1 = *reinterpret_cast<const float4*>(&As[k][64 + 4 * ty]);
                float4 b0 = *reinterpret_cast<const float4*>(&Bs[k][4 * tx]);
                float4 b1 = *reinterpret_cast<const float4*>(&Bs[k][64 + 4 * tx]);
                float a[8] = {a0.x, a0.y, a0.z, a0.w, a1.x, a1.y, a1.z, a1.w};
                float bb[8] = {b0.x, b0.y, b0.z, b0.w, b1.x, b1.y, b1.z, b1.w};
#pragma unroll
                for (int i = 0; i < 8; ++i)
#pragma unroll
                    for (int j = 0; j < 8; ++j)
                        acc[i][j] = fmaf(a[i], bb[j], acc[i][j]);
            }
        }
#pragma unroll
        for (int i = 0; i < 8; ++i) {
            int rl = (i < 4) ? (4 * ty + i) : (64 + 4 * ty + i - 4);
            int tgti = tgt_s[rl];
            float vmax = -INFINITY; int vidx = 0;
            float p = -INFINITY, ng = -INFINITY;
#pragma unroll
            for (int j = 0; j < 8; ++j) {
                int cl = (j < 4) ? (4 * tx + j) : (64 + 4 * tx + j - 4);
                float v = acc[i][j];
                int gk = key0 + cl;
                if (v > vmax) { vmax = v; vidx = gk; }
                bool corr = (mv_s[cl] == tgti);
                p  = fmaxf(p,  corr ? v : 0.f);
                ng = fmaxf(ng, corr ? 0.f : v);
            }
#pragma unroll
            for (int off = 1; off < 16; off <<= 1) {
                float om = __shfl_xor(vmax, off, 16);
                int   oi = __shfl_xor(vidx, off, 16);
                float op = __shfl_xor(p,    off, 16);
                float on = __shfl_xor(ng,   off, 16);
                if (om > vmax || (om == vmax && oi < vidx)) { vmax = om; vidx = oi; }
                p = fmaxf(p, op); ng = fmaxf(ng, on);
            }
            if (tx == 0) {
                if (vmax > run_max[rl]) { run_max[rl] = vmax; run_idx[rl] = vidx; }
                run_pos[rl] = fmaxf(run_pos[rl], p);
                run_neg[rl] = fmaxf(run_neg[rl], ng);
            }
        }
        __syncthreads();
    }
    if (t < BM) {
        int row = r0 + t;
        size_t o = (size_t)row * 16 + chunk;
        pmax[o] = run_max[t]; pidx[o] = run_idx[t];
        ppos[o] = run_pos[t]; pneg[o] = run_neg[t];
    }
}

__global__ __launch_bounds__(256) void k_merge_fb(
    const int* __restrict__ mvals, const int* __restrict__ tgt,
    const float* __restrict__ pmax, const int* __restrict__ pidx,
    const float* __restrict__ ppos, const float* __restrict__ pneg,
    float* __restrict__ out, float* __restrict__ means, int nch)
{
    __shared__ int counts[NCLS];
    __shared__ float perloc[256];
    __shared__ int haspos;
    const int b = blockIdx.x, t = threadIdx.x;
    if (t == 0) haspos = 0;
    if (t < NCLS) counts[t] = 0;
    perloc[t] = 0.f;
    __syncthreads();
    const int tg = tgt[b];
    int found = 0;
    for (int i = t; i < MSZ; i += 256) found |= (mvals[i] == tg) ? 1 : 0;
    if (found) atomicOr(&haspos, 1);
    __syncthreads();
    if (t < NHW) {
        int row = b * NHW + t;
        float vmax = -INFINITY; int vidx = 0;
        float p = -INFINITY, ng = -INFINITY;
        for (int c = 0; c < nch; ++c) {
            size_t o = (size_t)row * nch + c;
            float m = pmax[o]; int i_ = pidx[o];
            if (m > vmax || (m == vmax && i_ < vidx)) { vmax = m; vidx = i_; }
            p = fmaxf(p, ppos[o]); ng = fmaxf(ng, pneg[o]);
        }
        atomicAdd(&counts[mvals[vidx]], 1);
        perloc[t] = haspos ? fmaxf(ng - p + ALPHA, 0.f)
                           : fmaxf(ng + ALPHA, 0.f);
    }
    __syncthreads();
    for (int s = 128; s > 0; s >>= 1) {
        if (t < s) perloc[t] += perloc[t + s];
        __syncthreads();
    }
    if (t == 0) {
        int bestc = 0, bestn = counts[0];
        for (int c = 1; c < NCLS; ++c)
            if (counts[c] > bestn) { bestn = counts[c]; bestc = c; }
        out[b] = (float)bestc;
        means[b] = perloc[0] / (float)NHW;
    }
}

extern "C" void kernel_launch(void* const* d_in, const int* in_sizes, int n_in,
                              void* d_out, int out_size, void* d_ws, size_t ws_size,
                              hipStream_t stream) {
    const float* q  = (const float*)d_in[0];
    const int*   tg = (const int*)d_in[1];
    const float* mk = (const float*)d_in[2];
    const int*   mv = (const int*)d_in[3];
    float* out = (float*)d_out;

    unsigned short* khi = (unsigned short*)d_ws;                     // 16.8 MB
    unsigned short* qhi = khi + (size_t)MSZ * CDIM;                  // 6.6 MB
    float* qn     = (float*)(qhi + (size_t)MPAD * CDIM);             // 13.1 MB
    float* ssq4   = qn + (size_t)MPAD * CDIM;                        // 100 KB
    float* pmax32 = ssq4 + (size_t)M_ROWS * 4;                       // 13.1 MB
    float* ppos   = pmax32 + (size_t)MPAD * 512;                     // 3.3 MB
    float* pneg   = ppos + (size_t)MPAD * 128;                       // 3.3 MB
    int*   gcount = (int*)(pneg + (size_t)MPAD * 128);               // 2 KB
    unsigned short* gtasks = (unsigned short*)(gcount + 512);        // 6.4 MB
    unsigned long long* packed = (unsigned long long*)(gtasks + (size_t)512 * M_ROWS); // 50 KB
    float* means  = (float*)(packed + M_ROWS);
    size_t need = (size_t)((char*)(means + BSZ) - (char*)d_ws);

    if (ws_size >= need) {
        k_prep<<<128 + (MSZ * 128) / 256, 256, 0, stream>>>(q, ssq4, gcount, mk, khi);
        k_decomp_q<<<1600, 256, 0, stream>>>(q, ssq4, qhi, qn);
        k_mfma<<<6400, 256, 0, stream>>>(qhi, khi, mv, tg, pmax32, ppos, pneg);
        k_plan<<<M_ROWS, 256, 0, stream>>>(pmax32, gcount, gtasks, packed);
        k_redot<<<512, 256, 0, stream>>>(qn, mk, gcount, gtasks, packed);
        k_merge<<<BSZ, 256, 0, stream>>>(mv, tg, packed, ppos, pneg, out, means);
        k_final<<<1, 64, 0, stream>>>(means, out);
    } else {
        float* invq0  = (float*)d_ws;
        float* pmax0  = invq0 + M_ROWS;
        float* ppos0  = pmax0 + (size_t)M_ROWS * 16;
        float* pneg0  = ppos0 + (size_t)M_ROWS * 16;
        int*   pidx0  = (int*)(pneg0 + (size_t)M_ROWS * 16);
        float* means0 = (float*)(pidx0 + (size_t)M_ROWS * 16);
        k_invnorm<<<BSZ, 256, 0, stream>>>(q, invq0);
        k_gemm_reduce<<<49 * 16, 256, 0, stream>>>(q, mk, mv, tg, invq0,
                                                   pmax0, pidx0, ppos0, pneg0);
        k_merge_fb<<<BSZ, 256, 0, stream>>>(mv, tg, pmax0, pidx0, ppos0, pneg0, out, means0, 16);
        k_final<<<1, 64, 0, stream>>>(means0, out);
    }
}

// Round 14
// 244.294 us; speedup vs baseline: 1.3403x; 1.0232x over previous
//
#include <hip/hip_runtime.h>
#include <hip/hip_bf16.h>
#include <math.h>

typedef __attribute__((ext_vector_type(8))) short short8b;
typedef __attribute__((ext_vector_type(4))) float f32x4;

#define BSZ 32
#define NHW 196
#define M_ROWS 6272
#define MPAD 6400
#define CDIM 512
#define MSZ 16384
#define NCLS 100
#define ALPHA 0.1f
#define RSTR 67   // odd stride: ~2-way (free) banks on serial reduce reads

// ---------------- fused: invnorm partials (+counter zero) | bf16 K decomp ----------------
__global__ __launch_bounds__(256) void k_prep(
    const float* __restrict__ q, float* __restrict__ ssq4, int* __restrict__ gcount,
    const float* __restrict__ K, unsigned short* __restrict__ khi)
{
    const int bid = blockIdx.x;
    if (bid < 128) {
        const int b = bid >> 2, cc = bid & 3, n = threadIdx.x;
        if (bid == 0) { gcount[n] = 0; gcount[256 + n] = 0; }
        if (n >= NHW) return;
        const float* base = q + ((size_t)b * CDIM + cc * 128) * NHW + n;
        float ss = 0.f;
#pragma unroll 8
        for (int c = 0; c < 128; ++c) { float v = base[(size_t)c * NHW]; ss = fmaf(v, v, ss); }
        ssq4[(size_t)(b * NHW + n) * 4 + cc] = ss;
    } else {
        const int tid = (bid - 128) * 256 + threadIdx.x;
        const int c4 = tid & 127, key = tid >> 7;
        const int c = c4 << 2;
        const float4 v = *reinterpret_cast<const float4*>(K + (size_t)key * CDIM + c);
        float xs[4] = {v.x, v.y, v.z, v.w};
        unsigned short hs[4];
#pragma unroll
        for (int i = 0; i < 4; ++i) {
            __hip_bfloat16 h = __float2bfloat16(xs[i]);
            hs[i] = *(unsigned short*)&h;
        }
        size_t off = ((size_t)(c >> 5) * MSZ + key) * 32 + (c & 31);
        ushort4 H; H.x = hs[0]; H.y = hs[1]; H.z = hs[2]; H.w = hs[3];
        *reinterpret_cast<ushort4*>(khi + off) = H;
    }
}

// ---------------- normalized Q: bf16 (MFMA layout) + fp32 row-major (repair) ----------------
__global__ __launch_bounds__(256) void k_decomp_q(
    const float* __restrict__ Q, const float* __restrict__ ssq4,
    unsigned short* __restrict__ qhi, float* __restrict__ qn)
{
    __shared__ unsigned short lh[32][65];
    __shared__ float fs[32][65];
    const int t = threadIdx.x;
    const int rb = blockIdx.x % 100, kb = blockIdx.x / 100;
    const int r0 = rb * 64, c0 = kb * 32;
    const int cin = t >> 6, rin = t & 63;
    const int r = r0 + rin;
    float iv = 0.f;
    if (r < M_ROWS) {
        const float4 s4 = *reinterpret_cast<const float4*>(ssq4 + (size_t)r * 4);
        iv = 1.f / fmaxf(sqrtf((s4.x + s4.y) + (s4.z + s4.w)), 1e-12f);
    }
    const int b = r / NHW, n = r - b * NHW;
#pragma unroll
    for (int ci = 0; ci < 8; ++ci) {
        int cl = ci * 4 + cin;
        float x = 0.f;
        if (r < M_ROWS) x = Q[((size_t)(b * CDIM + (c0 + cl))) * NHW + n] * iv;
        __hip_bfloat16 h = __float2bfloat16(x);
        lh[cl][rin] = *(unsigned short*)&h;
        fs[cl][rin] = x;
    }
    __syncthreads();
    const int r2 = t >> 2, seg = t & 3;
    short8b vh;
    float4 f0, f1;
#pragma unroll
    for (int i = 0; i < 8; ++i) vh[i] = (short)lh[seg * 8 + i][r2];
    f0.x = fs[seg * 8 + 0][r2]; f0.y = fs[seg * 8 + 1][r2];
    f0.z = fs[seg * 8 + 2][r2]; f0.w = fs[seg * 8 + 3][r2];
    f1.x = fs[seg * 8 + 4][r2]; f1.y = fs[seg * 8 + 5][r2];
    f1.z = fs[seg * 8 + 6][r2]; f1.w = fs[seg * 8 + 7][r2];
    size_t off = ((size_t)kb * MPAD + r0 + r2) * 32 + seg * 8;
    *(short8b*)(qhi + off) = vh;
    float* qb = qn + (size_t)(r0 + r2) * CDIM + c0 + seg * 8;
    *reinterpret_cast<float4*>(qb) = f0;
    *reinterpret_cast<float4*>(qb + 4) = f1;
}

// ---------------- single-term bf16 MFMA GEMM + LDS-transpose epilogue (round-10 best) ----------------
__device__ __forceinline__ void gload16(const void* g, void* lds) {
    __builtin_amdgcn_global_load_lds((const __attribute__((address_space(1))) void*)g,
                                     (__attribute__((address_space(3))) void*)lds,
                                     16, 0, 0);
}

__global__ __launch_bounds__(256, 4) void k_mfma(
    const unsigned short* __restrict__ qhi, const unsigned short* __restrict__ khi,
    const int* __restrict__ mvals, const int* __restrict__ tgt,
    float* __restrict__ pmax32, float* __restrict__ ppos, float* __restrict__ pneg)
{
    __shared__ __align__(16) float red[128 * RSTR];   // 34.3 KB; aliased for staging
    __shared__ int mv_s[128];
    char* smem = (char*)red;                          // K-loop staging (32 KB)

    const int tid = threadIdx.x;
    const int w = tid >> 6, l = tid & 63;

    const int xcd = blockIdx.x & 7;
    const int idx = blockIdx.x >> 3;
    const int mt = idx >> 4;
    const int nt = (xcd << 4) | (idx & 15);
    const int r0 = mt * 128, n0 = nt * 128;

    const int srow = l >> 2;
    const int sg8 = (((l & 3) ^ ((l >> 3) & 3)) << 3);
    const int fr = l & 15;
    const int abyte = (fr << 6) + ((((l >> 4) ^ ((l >> 1) & 3))) << 4);

    const int wm = w >> 1, wn = w & 1;
    const int arow0 = wm * 64, bcol0 = wn * 64;

    f32x4 acc[4][4];
    const f32x4 zero4 = {0.f, 0.f, 0.f, 0.f};
#pragma unroll
    for (int m = 0; m < 4; ++m)
#pragma unroll
        for (int n = 0; n < 4; ++n) acc[m][n] = zero4;

    if (tid < 128) mv_s[tid] = mvals[n0 + tid];

    for (int ks = 0; ks < 8; ++ks) {
        __syncthreads();
#pragma unroll
        for (int h = 0; h < 2; ++h) {
            const int kb = 2 * ks + h;
            const size_t qb = ((size_t)kb * MPAD + r0) * 32;
            const size_t ko = ((size_t)kb * MSZ + n0) * 32;
#pragma unroll
            for (int j = 0; j < 2; ++j) {
                const int rr = w * 32 + j * 16 + srow;
                const int dst = h * 8192 + w * 2048 + j * 1024;
                gload16(qhi + qb + (size_t)rr * 32 + sg8, smem + dst);
                gload16(khi + ko + (size_t)rr * 32 + sg8, smem + 16384 + dst);
            }
        }
        __syncthreads();
#pragma unroll
        for (int h = 0; h < 2; ++h) {
            const char* bq = smem + h * 8192;
            const char* bk = smem + 16384 + h * 8192;
            short8b bh[4], ah[4];
#pragma unroll
            for (int n = 0; n < 4; ++n)
                bh[n] = *(const short8b*)(bk + ((bcol0 + n * 16) << 6) + abyte);
#pragma unroll
            for (int m = 0; m < 4; ++m)
                ah[m] = *(const short8b*)(bq + ((arow0 + m * 16) << 6) + abyte);
#pragma unroll
            for (int m = 0; m < 4; ++m)
#pragma unroll
                for (int n = 0; n < 4; ++n)
                    acc[m][n] = __builtin_amdgcn_mfma_f32_16x16x32_bf16(ah[m], bh[n], acc[m][n], 0, 0, 0);
        }
    }
    __syncthreads();   // all LDS reads done; red[] now reusable

    // ---- hoisted correctness masks: a 128-row tile spans <= 2 samples ----
    const int s0 = r0 / NHW;
    int s1 = (r0 + 127) / NHW; if (s1 > 31) s1 = 31;
    const int tg0 = tgt[s0], tg1 = tgt[s1];
    bool c0m[4], c1m[4];
#pragma unroll
    for (int n = 0; n < 4; ++n) {
        const int cl = bcol0 + n * 16 + fr;
        c0m[n] = (mv_s[cl] == tg0);
        c1m[n] = (mv_s[cl] == tg1);
    }

    // ---- pass 1: p/ng partials -> LDS transpose-reduce ----
#pragma unroll
    for (int m = 0; m < 4; ++m) {
#pragma unroll
        for (int rg = 0; rg < 4; ++rg) {
            const int rloc = arow0 + m * 16 + ((l >> 4) << 2) + rg;
            const int rglob = r0 + rloc;
            int samp = rglob / NHW; samp = samp > 31 ? 31 : samp;
            const bool use0 = (samp == s0);
            float p = -INFINITY, ng = -INFINITY;
#pragma unroll
            for (int n = 0; n < 4; ++n) {
                const float v = acc[m][n][rg];
                const bool corr = use0 ? c0m[n] : c1m[n];
                p  = fmaxf(p,  corr ? v : 0.f);   // mask-by-multiply semantics
                ng = fmaxf(ng, corr ? 0.f : v);
            }
            red[rloc * RSTR + (wn << 4) + fr] = p;
            red[rloc * RSTR + 34 + (wn << 4) + fr] = ng;
        }
    }
    __syncthreads();
    {
        const int row = tid & 127;
        const int base = row * RSTR + ((tid < 128) ? 0 : 34);
        float v = red[base];
#pragma unroll 31
        for (int i = 1; i < 32; ++i) v = fmaxf(v, red[base + i]);
        if (tid < 128) ppos[(size_t)nt * MPAD + r0 + row] = v;
        else           pneg[(size_t)nt * MPAD + r0 + row] = v;
    }
    __syncthreads();

    // ---- pass 2: per-32-key-group maxima -> LDS transpose-reduce ----
#pragma unroll
    for (int m = 0; m < 4; ++m) {
#pragma unroll
        for (int rg = 0; rg < 4; ++rg) {
            const int rloc = arow0 + m * 16 + ((l >> 4) << 2) + rg;
            const float vh0 = fmaxf(acc[m][0][rg], acc[m][1][rg]);
            const float vh1 = fmaxf(acc[m][2][rg], acc[m][3][rg]);
            red[rloc * RSTR + (wn << 5) + fr] = vh0;
            red[rloc * RSTR + (wn << 5) + 16 + fr] = vh1;
        }
    }
    __syncthreads();
#pragma unroll
    for (int uu = 0; uu < 2; ++uu) {
        const int u = tid + uu * 256;        // 512 units: (row, grp)
        const int row = u >> 2, grp = u & 3;
        const int base = row * RSTR + (grp << 4);
        float v = red[base];
#pragma unroll 15
        for (int i = 1; i < 16; ++i) v = fmaxf(v, red[base + i]);
        pmax32[(size_t)(r0 + row) * 512 + (nt << 2) + grp] = v;
    }
}

// ---------------- repair pass 1: per-row band scan -> per-group task lists ----------------
// |sim_bf16 - sim_exact| <= 2*2^-9 + eps; candidates in groups with pm >= M - 0.010.
__global__ __launch_bounds__(256) void k_plan(
    const float* __restrict__ pmax32,
    int* __restrict__ gcount, unsigned short* __restrict__ gtasks,
    unsigned long long* __restrict__ packed)
{
    __shared__ float redm[4];
    const int row = blockIdx.x, t = threadIdx.x;
    const float m0 = pmax32[(size_t)row * 512 + t];
    const float m1 = pmax32[(size_t)row * 512 + 256 + t];
    float m = fmaxf(m0, m1);
#pragma unroll
    for (int off = 1; off < 64; off <<= 1) m = fmaxf(m, __shfl_xor(m, off));
    if ((t & 63) == 0) redm[t >> 6] = m;
    __syncthreads();
    const float M = fmaxf(fmaxf(redm[0], redm[1]), fmaxf(redm[2], redm[3]));
    const float thr = M - 0.010f;
    if (t == 0) packed[row] = 0ull;
    if (m0 >= thr) {
        int s = atomicAdd(&gcount[t], 1);
        gtasks[(size_t)t * M_ROWS + s] = (unsigned short)row;
    }
    if (m1 >= thr) {
        int s = atomicAdd(&gcount[256 + t], 1);
        gtasks[(size_t)(256 + t) * M_ROWS + s] = (unsigned short)row;
    }
}

// ---------------- repair pass 2: group-major exact fp32 re-dot ----------------
__device__ __forceinline__ unsigned long long enc_vi(float v, int idx) {
    unsigned u = __float_as_uint(v);
    u = (u & 0x80000000u) ? ~u : (u | 0x80000000u);   // order-preserving
    return ((unsigned long long)u << 32) | (unsigned)(0xFFFFFFFFu - (unsigned)idx);
}

__global__ __launch_bounds__(256, 2) void k_redot(
    const float* __restrict__ qn, const float* __restrict__ mk,
    const int* __restrict__ gcount, const unsigned short* __restrict__ gtasks,
    unsigned long long* __restrict__ packed)
{
    __shared__ float ks[32][516];
    __shared__ float qrow[512];
    __shared__ float part[32][9];
    const int g = blockIdx.x, t = threadIdx.x;
    const int cnt = gcount[g];
    if (cnt == 0) return;
    {
        const float4* src = reinterpret_cast<const float4*>(mk + (size_t)g * 32 * CDIM);
        for (int i = t; i < 4096; i += 256) {
            const int key = i >> 7, pos = i & 127;
            *reinterpret_cast<float4*>(&ks[key][pos << 2]) = src[i];
        }
    }
    const int kj = t & 31, seg = t >> 5;
    for (int i = 0; i < cnt; ++i) {
        const int row = gtasks[(size_t)g * M_ROWS + i];
        *reinterpret_cast<float2*>(&qrow[t * 2]) =
            *reinterpret_cast<const float2*>(qn + (size_t)row * CDIM + t * 2);
        __syncthreads();
        float s = 0.f;
        const float4* kr = reinterpret_cast<const float4*>(&ks[kj][seg * 64]);
        const float4* qr = reinterpret_cast<const float4*>(&qrow[seg * 64]);
#pragma unroll
        for (int u = 0; u < 16; ++u) {
            const float4 a = qr[u], b = kr[u];
            s = fmaf(a.x, b.x, s); s = fmaf(a.y, b.y, s);
            s = fmaf(a.z, b.z, s); s = fmaf(a.w, b.w, s);
        }
        part[kj][seg] = s;
        __syncthreads();
        if (t < 32) {
            float sim = ((part[t][0] + part[t][1]) + (part[t][2] + part[t][3]))
                      + ((part[t][4] + part[t][5]) + (part[t][6] + part[t][7]));
            int ki = g * 32 + t;
#pragma unroll
            for (int off = 1; off < 32; off <<= 1) {
                const float ov = __shfl_xor(sim, off);
                const int   oi = __shfl_xor(ki, off);
                if (ov > sim || (ov == sim && oi < ki)) { sim = ov; ki = oi; }
            }
            if (t == 0)
                atomicMax((unsigned long long*)&packed[row], enc_vi(sim, ki));
        }
        __syncthreads();
    }
}

// ---------------- merge + vote + loss (repaired argmax) ----------------
__global__ __launch_bounds__(256) void k_merge(
    const int* __restrict__ mvals, const int* __restrict__ tgt,
    const unsigned long long* __restrict__ packed,
    const float* __restrict__ ppos, const float* __restrict__ pneg,
    float* __restrict__ out, float* __restrict__ means)
{
    __shared__ int counts[NCLS];
    __shared__ float perloc[256];
    __shared__ int haspos;
    const int b = blockIdx.x, t = threadIdx.x;
    if (t == 0) haspos = 0;
    if (t < NCLS) counts[t] = 0;
    perloc[t] = 0.f;
    __syncthreads();
    const int tg = tgt[b];
    int found = 0;
    for (int i = t; i < MSZ; i += 256) found |= (mvals[i] == tg) ? 1 : 0;
    if (found) atomicOr(&haspos, 1);
    __syncthreads();
    if (t < NHW) {
        const int row = b * NHW + t;
        float p = -INFINITY, ng = -INFINITY;
        for (int c = 0; c < 128; ++c) {      // [chunk][row]: coalesced across t
            p  = fmaxf(p,  ppos[(size_t)c * MPAD + row]);
            ng = fmaxf(ng, pneg[(size_t)c * MPAD + row]);
        }
        const int ri = (int)(0xFFFFFFFFu - (unsigned)(packed[row] & 0xFFFFFFFFull));
        atomicAdd(&counts[mvals[ri]], 1);
        perloc[t] = haspos ? fmaxf(ng - p + ALPHA, 0.f)
                           : fmaxf(ng + ALPHA, 0.f);
    }
    __syncthreads();
    for (int s = 128; s > 0; s >>= 1) {
        if (t < s) perloc[t] += perloc[t + s];
        __syncthreads();
    }
    if (t == 0) {
        int bestc = 0, bestn = counts[0];
        for (int c = 1; c < NCLS; ++c)
            if (counts[c] > bestn) { bestn = counts[c]; bestc = c; }
        out[b] = (float)bestc;
        means[b] = perloc[0] / (float)NHW;
    }
}

__global__ __launch_bounds__(64) void k_final(const float* __restrict__ means,
                                              float* __restrict__ out) {
    if (threadIdx.x == 0) {
        float s = 0.f;
        for (int b = 0; b < BSZ; ++b) s += means[b];
        out[BSZ] = s;
    }
}

// ---------------- fp32 fallback path (round-1 verified) ----------------
#define BM 128
#define BN 128
#define BK 16
#define LDA (BM + 4)
#define LDB (BN + 4)

__global__ __launch_bounds__(256) void k_invnorm(const float* __restrict__ q,
                                                 float* __restrict__ invq) {
    int b = blockIdx.x, n = threadIdx.x;
    if (n >= NHW) return;
    const float* base = q + (size_t)b * CDIM * NHW + n;
    float ss = 0.f;
#pragma unroll 4
    for (int c = 0; c < CDIM; ++c) { float v = base[(size_t)c * NHW]; ss = fmaf(v, v, ss); }
    invq[b * NHW + n] = 1.f / fmaxf(sqrtf(ss), 1e-12f);
}

__global__ __launch_bounds__(256) void k_gemm_reduce(
    const float* __restrict__ Q, const float* __restrict__ Kz,
    const int* __restrict__ mvals, const int* __restrict__ tgt,
    const float* __restrict__ invq,
    float* __restrict__ pmax, int* __restrict__ pidx,
    float* __restrict__ ppos, float* __restrict__ pneg)
{
    __shared__ float As[BK][LDA];
    __shared__ float Bs[BK][LDB];
    __shared__ float run_max[BM];
    __shared__ int   run_idx[BM];
    __shared__ float run_pos[BM];
    __shared__ float run_neg[BM];
    __shared__ int   mv_s[BN];
    __shared__ int   tgt_s[BM];
    __shared__ float inv_s[BM];

    const int t = threadIdx.x;
    const int rt = blockIdx.x % 49;
    const int chunk = blockIdx.x / 49;
    const int r0 = rt * BM;

    if (t < BM) {
        run_max[t] = -INFINITY; run_idx[t] = 0;
        run_pos[t] = -INFINITY; run_neg[t] = -INFINITY;
        int row = r0 + t;
        tgt_s[t] = tgt[row / NHW];
        inv_s[t] = invq[row];
    }
    const int ty = t >> 4, tx = t & 15;
    __syncthreads();

    for (int tile = 0; tile < 8; ++tile) {
        const int key0 = chunk * 1024 + tile * BN;
        if (t < BN) mv_s[t] = mvals[key0 + t];
        float acc[8][8];
#pragma unroll
        for (int i = 0; i < 8; ++i)
#pragma unroll
            for (int j = 0; j < 8; ++j) acc[i][j] = 0.f;

        for (int ks = 0; ks < 32; ++ks) {
            const int c0 = ks * BK;
            __syncthreads();
#pragma unroll
            for (int it = 0; it < 2; ++it) {
                int i = t + it * 256;
                int k = i >> 5;
                int r4 = (i & 31) << 2;
                int row = r0 + r4;
                int b = row / NHW;
                int n = row - b * NHW;
                const float4 v = *reinterpret_cast<const float4*>(
                    Q + ((size_t)(b * CDIM + c0 + k)) * NHW + n);
                float4 w;
                w.x = v.x * inv_s[r4 + 0]; w.y = v.y * inv_s[r4 + 1];
                w.z = v.z * inv_s[r4 + 2]; w.w = v.w * inv_s[r4 + 3];
                *reinterpret_cast<float4*>(&As[k][r4]) = w;
            }
#pragma unroll
            for (int it = 0; it < 2; ++it) {
                int i = t + it * 256;
                int key = i >> 2;
                int cc = (i & 3) << 2;
                const float4 v = *reinterpret_cast<const float4*>(
                    Kz + (size_t)(key0 + key) * CDIM + c0 + cc);
                Bs[cc + 0][key] = v.x; Bs[cc + 1][key] = v.y;
                Bs[cc + 2][key] = v.z; Bs[cc + 3][key] = v.w;
            }
            __syncthreads();
#pragma unroll
            for (int k = 0; k < BK; ++k) {
                float4 a0 = *reinterpret_cast<const float4*>(&As[k][4 * ty]);
                float4 a1 = *reinterpret_cast<const float4*>(&As[k][64 + 4 * ty]);
                float4 b0 = *reinterpret_cast<const float4*>(&Bs[k][4 * tx]);
                float4 b1 = *reinterpret_cast<const float4*>(&Bs[k][64 + 4 * tx]);
                float a[8] = {a0.x, a0.y, a0.z, a0.w, a1.x, a1.y, a1.z, a1.w};
                float bb[8] = {b0.x, b0.y, b0.z, b0.w, b1.x, b1.y, b1.z, b1.w};
#pragma unroll
                for (int i = 0; i < 8; ++i)
#pragma unroll
                    for (int j = 0; j < 8; ++j)
                        acc[i][j] = fmaf(a[i], bb[j], acc[i][j]);
            }
        }
#pragma unroll
        for (int i = 0; i < 8; ++i) {
            int rl = (i < 4) ? (4 * ty + i) : (64 + 4 * ty + i - 4);
            int tgti = tgt_s[rl];
            float vmax = -INFINITY; int vidx = 0;
            float p = -INFINITY, ng = -INFINITY;
#pragma unroll
            for (int j = 0; j < 8; ++j) {
                int cl = (j < 4) ? (4 * tx + j) : (64 + 4 * tx + j - 4);
                float v = acc[i][j];
                int gk = key0 + cl;
                if (v > vmax) { vmax = v; vidx = gk; }
                bool corr = (mv_s[cl] == tgti);
                p  = fmaxf(p,  corr ? v : 0.f);
                ng = fmaxf(ng, corr ? 0.f : v);
            }
#pragma unroll
            for (int off = 1; off < 16; off <<= 1) {
                float om = __shfl_xor(vmax, off, 16);
                int   oi = __shfl_xor(vidx, off, 16);
                float op = __shfl_xor(p,    off, 16);
                float on = __shfl_xor(ng,   off, 16);
                if (om > vmax || (om == vmax && oi < vidx)) { vmax = om; vidx = oi; }
                p = fmaxf(p, op); ng = fmaxf(ng, on);
            }
            if (tx == 0) {
                if (vmax > run_max[rl]) { run_max[rl] = vmax; run_idx[rl] = vidx; }
                run_pos[rl] = fmaxf(run_pos[rl], p);
                run_neg[rl] = fmaxf(run_neg[rl], ng);
            }
        }
        __syncthreads();
    }
    if (t < BM) {
        int row = r0 + t;
        size_t o = (size_t)row * 16 + chunk;
        pmax[o] = run_max[t]; pidx[o] = run_idx[t];
        ppos[o] = run_pos[t]; pneg[o] = run_neg[t];
    }
}

__global__ __launch_bounds__(256) void k_merge_fb(
    const int* __restrict__ mvals, const int* __restrict__ tgt,
    const float* __restrict__ pmax, const int* __restrict__ pidx,
    const float* __restrict__ ppos, const float* __restrict__ pneg,
    float* __restrict__ out, float* __restrict__ means, int nch)
{
    __shared__ int counts[NCLS];
    __shared__ float perloc[256];
    __shared__ int haspos;
    const int b = blockIdx.x, t = threadIdx.x;
    if (t == 0) haspos = 0;
    if (t < NCLS) counts[t] = 0;
    perloc[t] = 0.f;
    __syncthreads();
    const int tg = tgt[b];
    int found = 0;
    for (int i = t; i < MSZ; i += 256) found |= (mvals[i] == tg) ? 1 : 0;
    if (found) atomicOr(&haspos, 1);
    __syncthreads();
    if (t < NHW) {
        int row = b * NHW + t;
        float vmax = -INFINITY; int vidx = 0;
        float p = -INFINITY, ng = -INFINITY;
        for (int c = 0; c < nch; ++c) {
            size_t o = (size_t)row * nch + c;
            float m = pmax[o]; int i_ = pidx[o];
            if (m > vmax || (m == vmax && i_ < vidx)) { vmax = m; vidx = i_; }
            p = fmaxf(p, ppos[o]); ng = fmaxf(ng, pneg[o]);
        }
        atomicAdd(&counts[mvals[vidx]], 1);
        perloc[t] = haspos ? fmaxf(ng - p + ALPHA, 0.f)
                           : fmaxf(ng + ALPHA, 0.f);
    }
    __syncthreads();
    for (int s = 128; s > 0; s >>= 1) {
        if (t < s) perloc[t] += perloc[t + s];
        __syncthreads();
    }
    if (t == 0) {
        int bestc = 0, bestn = counts[0];
        for (int c = 1; c < NCLS; ++c)
            if (counts[c] > bestn) { bestn = counts[c]; bestc = c; }
        out[b] = (float)bestc;
        means[b] = perloc[0] / (float)NHW;
    }
}

extern "C" void kernel_launch(void* const* d_in, const int* in_sizes, int n_in,
                              void* d_out, int out_size, void* d_ws, size_t ws_size,
                              hipStream_t stream) {
    const float* q  = (const float*)d_in[0];
    const int*   tg = (const int*)d_in[1];
    const float* mk = (const float*)d_in[2];
    const int*   mv = (const int*)d_in[3];
    float* out = (float*)d_out;

    unsigned short* khi = (unsigned short*)d_ws;                     // 16.8 MB
    unsigned short* qhi = khi + (size_t)MSZ * CDIM;                  // 6.6 MB
    float* qn     = (float*)(qhi + (size_t)MPAD * CDIM);             // 13.1 MB
    float* ssq4   = qn + (size_t)MPAD * CDIM;                        // 100 KB
    float* pmax32 = ssq4 + (size_t)M_ROWS * 4;                       // 13.1 MB
    float* ppos   = pmax32 + (size_t)MPAD * 512;                     // 3.3 MB
    float* pneg   = ppos + (size_t)MPAD * 128;                       // 3.3 MB
    int*   gcount = (int*)(pneg + (size_t)MPAD * 128);               // 2 KB
    unsigned short* gtasks = (unsigned short*)(gcount + 512);        // 6.4 MB
    unsigned long long* packed = (unsigned long long*)(gtasks + (size_t)512 * M_ROWS); // 50 KB
    float* means  = (float*)(packed + M_ROWS);
    size_t need = (size_t)((char*)(means + BSZ) - (char*)d_ws);

    if (ws_size >= need) {
        k_prep<<<128 + (MSZ * 128) / 256, 256, 0, stream>>>(q, ssq4, gcount, mk, khi);
        k_decomp_q<<<1600, 256, 0, stream>>>(q, ssq4, qhi, qn);
        k_mfma<<<6400, 256, 0, stream>>>(qhi, khi, mv, tg, pmax32, ppos, pneg);
        k_plan<<<M_ROWS, 256, 0, stream>>>(pmax32, gcount, gtasks, packed);
        k_redot<<<512, 256, 0, stream>>>(qn, mk, gcount, gtasks, packed);
        k_merge<<<BSZ, 256, 0, stream>>>(mv, tg, packed, ppos, pneg, out, means);
        k_final<<<1, 64, 0, stream>>>(means, out);
    } else {
        float* invq0  = (float*)d_ws;
        float* pmax0  = invq0 + M_ROWS;
        float* ppos0  = pmax0 + (size_t)M_ROWS * 16;
        float* pneg0  = ppos0 + (size_t)M_ROWS * 16;
        int*   pidx0  = (int*)(pneg0 + (size_t)M_ROWS * 16);
        float* means0 = (float*)(pidx0 + (size_t)M_ROWS * 16);
        k_invnorm<<<BSZ, 256, 0, stream>>>(q, invq0);
        k_gemm_reduce<<<49 * 16, 256, 0, stream>>>(q, mk, mv, tg, invq0,
                                                   pmax0, pidx0, ppos0, pneg0);
        k_merge_fb<<<BSZ, 256, 0, stream>>>(mv, tg, pmax0, pidx0, ppos0, pneg0, out, means0, 16);
        k_final<<<1, 64, 0, stream>>>(means0, out);
    }
}